// Round 2
// baseline (3155.761 us; speedup 1.0000x reference)
//
#include <hip/hip_runtime.h>
#include <math.h>

// Problem constants
#define BB 4
#define SS 1024
#define DD 256
#define HH 8
#define HD 32
#define D3 768
#define MLP 1024
#define NTOK (BB * SS)   // 4096

// ---------------------------------------------------------------------------
// x (f32) + positional encoding -> fp32
__global__ __launch_bounds__(256) void add_pos_kernel(
    const float* __restrict__ x, const float* __restrict__ scale,
    float* __restrict__ out, int n)
{
    int i = blockIdx.x * 256 + threadIdx.x;
    if (i >= n) return;
    int s = (i >> 8) & (SS - 1);          // D=256 -> i>>8 ; mod S
    out[i] = x[i] + (float)s * scale[0];
}

// ---------------------------------------------------------------------------
// C[M,N] = A[M,K](f32) @ W[N,K]^T(f32) + bias(f32)  [+gelu] [+resid(f32)]
// 64x64 tile, 256 threads, 4x4 per thread, BK=16. M,N %64==0, K %16==0.
#define Bb 64
#define BKK 16
__global__ __launch_bounds__(256) void gemm_bias(
    const float* __restrict__ A, const float* __restrict__ W,
    const float* __restrict__ bias, const float* __restrict__ resid,
    float* __restrict__ C, int M, int N, int K, int act)
{
    __shared__ float As[BKK][Bb + 1];
    __shared__ float Ws[BKK][Bb + 1];
    const int tx = threadIdx.x & 15, ty = threadIdx.x >> 4;
    const int m0 = blockIdx.y * Bb, n0 = blockIdx.x * Bb;
    const int lr = threadIdx.x >> 2;        // 0..63
    const int lc = (threadIdx.x & 3) * 4;   // 0,4,8,12

    float acc[4][4] = {};
    for (int k0 = 0; k0 < K; k0 += BKK) {
        float4 av = *(const float4*)(A + (size_t)(m0 + lr) * K + k0 + lc);
        As[lc + 0][lr] = av.x; As[lc + 1][lr] = av.y;
        As[lc + 2][lr] = av.z; As[lc + 3][lr] = av.w;
        float4 wv = *(const float4*)(W + (size_t)(n0 + lr) * K + k0 + lc);
        Ws[lc + 0][lr] = wv.x; Ws[lc + 1][lr] = wv.y;
        Ws[lc + 2][lr] = wv.z; Ws[lc + 3][lr] = wv.w;
        __syncthreads();
        #pragma unroll
        for (int kk = 0; kk < BKK; kk++) {
            float a[4], bv[4];
            #pragma unroll
            for (int i = 0; i < 4; i++) a[i] = As[kk][ty * 4 + i];
            #pragma unroll
            for (int j = 0; j < 4; j++) bv[j] = Ws[kk][tx * 4 + j];
            #pragma unroll
            for (int i = 0; i < 4; i++)
                #pragma unroll
                for (int j = 0; j < 4; j++)
                    acc[i][j] += a[i] * bv[j];
        }
        __syncthreads();
    }
    #pragma unroll
    for (int i = 0; i < 4; i++) {
        int row = m0 + ty * 4 + i;
        #pragma unroll
        for (int j = 0; j < 4; j++) {
            int col = n0 + tx * 4 + j;
            float v = acc[i][j] + bias[col];
            if (act == 1) v = 0.5f * v * (1.0f + erff(v * 0.70710678118654752f));
            if (resid) v += resid[(size_t)row * N + col];
            C[(size_t)row * N + col] = v;
        }
    }
}

// ---------------------------------------------------------------------------
// Windowed attention over packed qkv (B,S,3D). One wave per query row.
// win >= S-1 -> full attention. out (B,S,D), heads concatenated.
__global__ __launch_bounds__(256) void attn_kernel(
    const float* __restrict__ qkv, float* __restrict__ out, int win)
{
    __shared__ float sS[4][SS];           // 16 KB
    const int w = threadIdx.x >> 6, lane = threadIdx.x & 63;
    const int i = blockIdx.x * 4 + w;
    const int h = blockIdx.y, b = blockIdx.z;
    int jlo = i - win; if (jlo < 0) jlo = 0;
    int jhi = i + win; if (jhi > SS - 1) jhi = SS - 1;
    const int n = jhi - jlo + 1;

    const float* qp = qkv + (size_t)(b * SS + i) * D3 + h * HD;
    float q[HD];
    #pragma unroll
    for (int d4 = 0; d4 < HD; d4 += 4) {
        float4 t = *(const float4*)(qp + d4);
        q[d4] = t.x; q[d4 + 1] = t.y; q[d4 + 2] = t.z; q[d4 + 3] = t.w;
    }
    const float scl = 0.17677669529663688f;  // 1/sqrt(32)

    float m = -1e30f;
    for (int jj = lane; jj < n; jj += 64) {
        const float* kp = qkv + (size_t)(b * SS + jlo + jj) * D3 + DD + h * HD;
        float s = 0.f;
        #pragma unroll
        for (int d4 = 0; d4 < HD; d4 += 4) {
            float4 t = *(const float4*)(kp + d4);
            s += q[d4] * t.x + q[d4 + 1] * t.y + q[d4 + 2] * t.z + q[d4 + 3] * t.w;
        }
        s *= scl;
        sS[w][jj] = s;
        m = fmaxf(m, s);
    }
    #pragma unroll
    for (int off = 32; off; off >>= 1) m = fmaxf(m, __shfl_xor(m, off, 64));

    float lsum = 0.f;
    for (int jj = lane; jj < n; jj += 64) {
        float e = __expf(sS[w][jj] - m);
        sS[w][jj] = e;
        lsum += e;
    }
    #pragma unroll
    for (int off = 32; off; off >>= 1) lsum += __shfl_xor(lsum, off, 64);
    const float inv = (lsum > 0.f) ? 1.0f / lsum : 0.f;

    __syncthreads();   // make exp values visible across lanes

    const int d = lane & 31;
    const int half = lane >> 5;   // even/odd j split across wave halves
    float o = 0.f;
    for (int jj = half; jj < n; jj += 2) {
        float p = sS[w][jj];
        o += p * qkv[(size_t)(b * SS + jlo + jj) * D3 + 2 * DD + h * HD + d];
    }
    o += __shfl_down(o, 32, 64);
    if (lane < 32)
        out[(size_t)(b * SS + i) * DD + h * HD + d] = o * inv;
}

// ---------------------------------------------------------------------------
// out = LN(a [+ r]) * g + b   — one block (256 thr) per row, D=256
__global__ __launch_bounds__(256) void ln_kernel(
    const float* __restrict__ a, const float* __restrict__ r,
    const float* __restrict__ g, const float* __restrict__ bt,
    float* __restrict__ outf)
{
    const int row = blockIdx.x, d = threadIdx.x;
    const size_t idx = (size_t)row * DD + d;
    float v = a[idx];
    if (r) v += r[idx];
    const int lane = d & 63, wid = d >> 6;
    float s = v;
    #pragma unroll
    for (int o = 32; o; o >>= 1) s += __shfl_xor(s, o, 64);
    __shared__ float r1[4], r2[4];
    if (lane == 0) r1[wid] = s;
    __syncthreads();
    float mean = (r1[0] + r1[1] + r1[2] + r1[3]) * (1.0f / 256.0f);
    float dv = v - mean;
    float s2 = dv * dv;
    #pragma unroll
    for (int o = 32; o; o >>= 1) s2 += __shfl_xor(s2, o, 64);
    if (lane == 0) r2[wid] = s2;
    __syncthreads();
    float var = (r2[0] + r2[1] + r2[2] + r2[3]) * (1.0f / 256.0f);
    outf[idx] = dv * rsqrtf(var + 1e-5f) * g[d] + bt[d];
}

// ---------------------------------------------------------------------------
extern "C" void kernel_launch(void* const* d_in, const int* in_sizes, int n_in,
                              void* d_out, int out_size, void* d_ws, size_t ws_size,
                              hipStream_t stream)
{
    const float* xin   = (const float*)d_in[0];
    const float* scale = (const float*)d_in[1];
    const float* Win_a = (const float*)d_in[2];
    const float* bin_a = (const float*)d_in[3];
    const float* Wout_a= (const float*)d_in[4];
    const float* bout_a= (const float*)d_in[5];
    const float* Win_e = (const float*)d_in[6];
    const float* bin_e = (const float*)d_in[7];
    const float* Wout_e= (const float*)d_in[8];
    const float* bout_e= (const float*)d_in[9];
    const float* ln1_g = (const float*)d_in[10];
    const float* ln1_b = (const float*)d_in[11];
    const float* ln2_g = (const float*)d_in[12];
    const float* ln2_b = (const float*)d_in[13];
    const float* W1    = (const float*)d_in[14];
    const float* b1    = (const float*)d_in[15];
    const float* W2    = (const float*)d_in[16];
    const float* b2    = (const float*)d_in[17];
    const float* lnf_g = (const float*)d_in[18];
    const float* lnf_b = (const float*)d_in[19];

    float* ws = (float*)d_ws;
    float* X   = ws;                       // 4096*256
    float* X2  = X   + (size_t)NTOK * DD;
    float* P   = X2  + (size_t)NTOK * DD;
    float* AT  = P   + (size_t)NTOK * DD;
    float* QKV = AT  + (size_t)NTOK * DD;  // 4096*768
    float* HML = QKV + (size_t)NTOK * D3;  // 4096*1024

    add_pos_kernel<<<(NTOK * DD + 255) / 256, 256, 0, stream>>>(xin, scale, X, NTOK * DD);

    float* cur = X;
    float* oth = X2;
    for (int l = 0; l < 2; l++) {
        const float* WinA  = Win_a  + (size_t)l * D3 * DD;
        const float* binA  = bin_a  + (size_t)l * D3;
        const float* WoutA = Wout_a + (size_t)l * DD * DD;
        const float* boutA = bout_a + (size_t)l * DD;
        const float* WinE  = Win_e  + (size_t)l * D3 * DD;
        const float* binE  = bin_e  + (size_t)l * D3;
        const float* WoutE = Wout_e + (size_t)l * DD * DD;
        const float* boutE = bout_e + (size_t)l * DD;
        const float* W1l   = W1 + (size_t)l * MLP * DD;
        const float* b1l   = b1 + (size_t)l * MLP;
        const float* W2l   = W2 + (size_t)l * DD * MLP;
        const float* b2l   = b2 + (size_t)l * DD;

        // --- full self-attention
        gemm_bias<<<dim3(D3 / Bb, NTOK / Bb), 256, 0, stream>>>(
            cur, WinA, binA, nullptr, QKV, NTOK, D3, DD, 0);
        attn_kernel<<<dim3(SS / 4, HH, BB), 256, 0, stream>>>(QKV, AT, SS);
        gemm_bias<<<dim3(DD / Bb, NTOK / Bb), 256, 0, stream>>>(
            AT, WoutA, boutA, nullptr, P, NTOK, DD, DD, 0);
        ln_kernel<<<NTOK, 256, 0, stream>>>(P, cur, ln1_g + l * DD, ln1_b + l * DD, oth);

        // --- banded self-attention (|i-j| <= 64)
        gemm_bias<<<dim3(D3 / Bb, NTOK / Bb), 256, 0, stream>>>(
            oth, WinE, binE, nullptr, QKV, NTOK, D3, DD, 0);
        attn_kernel<<<dim3(SS / 4, HH, BB), 256, 0, stream>>>(QKV, AT, 64);
        gemm_bias<<<dim3(DD / Bb, NTOK / Bb), 256, 0, stream>>>(
            AT, WoutE, boutE, nullptr, P, NTOK, DD, DD, 0);
        ln_kernel<<<NTOK, 256, 0, stream>>>(P, oth, ln2_g + l * DD, ln2_b + l * DD, cur);
        // attended now in cur

        // --- MLP with exact gelu, fused residual
        gemm_bias<<<dim3(MLP / Bb, NTOK / Bb), 256, 0, stream>>>(
            cur, W1l, b1l, nullptr, HML, NTOK, MLP, DD, 1);
        gemm_bias<<<dim3(DD / Bb, NTOK / Bb), 256, 0, stream>>>(
            HML, W2l, b2l, cur, oth, NTOK, DD, MLP, 0);

        float* t = cur; cur = oth; oth = t;   // x for next layer is in cur
    }

    ln_kernel<<<NTOK, 256, 0, stream>>>(cur, nullptr, lnf_g, lnf_b, (float*)d_out);
}

// Round 3
// 1070.716 us; speedup vs baseline: 2.9473x; 2.9473x over previous
//
#include <hip/hip_runtime.h>
#include <math.h>

// Problem constants
#define BB 4
#define SS 1024
#define DD 256
#define HH 8
#define HD 32
#define D3 768
#define MLP 1024
#define NTOK (BB * SS)   // 4096

// ---------------------------------------------------------------------------
// x (f32) + positional encoding -> fp32
__global__ __launch_bounds__(256) void add_pos_kernel(
    const float* __restrict__ x, const float* __restrict__ scale,
    float* __restrict__ out, int n)
{
    int i = blockIdx.x * 256 + threadIdx.x;
    if (i >= n) return;
    int s = (i >> 8) & (SS - 1);          // D=256 -> i>>8 ; mod S
    out[i] = x[i] + (float)s * scale[0];
}

// ---------------------------------------------------------------------------
// C[M,N] = A[M,K](f32) @ W[N,K]^T(f32) + bias(f32)  [+gelu] [+resid(f32)]
// 64x64 tile, 256 threads, 4x4 per thread, BK=16. M,N %64==0, K %16==0.
#define Bb 64
#define BKK 16
__global__ __launch_bounds__(256) void gemm_bias(
    const float* __restrict__ A, const float* __restrict__ W,
    const float* __restrict__ bias, const float* __restrict__ resid,
    float* __restrict__ C, int M, int N, int K, int act)
{
    __shared__ float As[BKK][Bb + 1];
    __shared__ float Ws[BKK][Bb + 1];
    const int tx = threadIdx.x & 15, ty = threadIdx.x >> 4;
    const int m0 = blockIdx.y * Bb, n0 = blockIdx.x * Bb;
    const int lr = threadIdx.x >> 2;        // 0..63
    const int lc = (threadIdx.x & 3) * 4;   // 0,4,8,12

    float acc[4][4] = {};
    for (int k0 = 0; k0 < K; k0 += BKK) {
        float4 av = *(const float4*)(A + (size_t)(m0 + lr) * K + k0 + lc);
        As[lc + 0][lr] = av.x; As[lc + 1][lr] = av.y;
        As[lc + 2][lr] = av.z; As[lc + 3][lr] = av.w;
        float4 wv = *(const float4*)(W + (size_t)(n0 + lr) * K + k0 + lc);
        Ws[lc + 0][lr] = wv.x; Ws[lc + 1][lr] = wv.y;
        Ws[lc + 2][lr] = wv.z; Ws[lc + 3][lr] = wv.w;
        __syncthreads();
        #pragma unroll
        for (int kk = 0; kk < BKK; kk++) {
            float a[4], bv[4];
            #pragma unroll
            for (int i = 0; i < 4; i++) a[i] = As[kk][ty * 4 + i];
            #pragma unroll
            for (int j = 0; j < 4; j++) bv[j] = Ws[kk][tx * 4 + j];
            #pragma unroll
            for (int i = 0; i < 4; i++)
                #pragma unroll
                for (int j = 0; j < 4; j++)
                    acc[i][j] += a[i] * bv[j];
        }
        __syncthreads();
    }
    #pragma unroll
    for (int i = 0; i < 4; i++) {
        int row = m0 + ty * 4 + i;
        #pragma unroll
        for (int j = 0; j < 4; j++) {
            int col = n0 + tx * 4 + j;
            float v = acc[i][j] + bias[col];
            if (act == 1) v = 0.5f * v * (1.0f + erff(v * 0.70710678118654752f));
            if (resid) v += resid[(size_t)row * N + col];
            C[(size_t)row * N + col] = v;
        }
    }
}

// ---------------------------------------------------------------------------
// Flash-style windowed attention. Block = 256 thr per (b, h, 64-query tile).
// qkv packed (B,S,3D). win >= S -> full attention. out (B,S,D).
__global__ __launch_bounds__(256) void attn_tile_kernel(
    const float* __restrict__ qkv, float* __restrict__ out, int win)
{
    __shared__ __align__(16) float Qs[64][36];   // 64x32, pad->36 (16B-aligned rows)
    __shared__ __align__(16) float Ks[64][36];
    __shared__ __align__(16) float Vt[HD][68];   // V transposed: [d][j]
    __shared__ __align__(16) float Ps[64][68];   // P tile

    const int t  = threadIdx.x;
    const int tx = t & 15, ty = t >> 4;          // 16 col-groups x 16 row-groups
    const int i0 = blockIdx.x * 64;
    const int h  = blockIdx.y, b = blockIdx.z;
    const int lr = t >> 3, lc4 = (t & 7) * 4;    // staging: 8 thr/row, float4 cols

    // ---- load Q tile (64x32) coalesced
    {
        const float* qp = qkv + ((size_t)(b * SS + i0 + lr)) * D3 + h * HD + lc4;
        *(float4*)&Qs[lr][lc4]      = *(const float4*)qp;
        *(float4*)&Qs[lr + 32][lc4] = *(const float4*)(qp + 32 * D3);
    }

    float m[4], l[4], o[4][2];
    #pragma unroll
    for (int i = 0; i < 4; i++) { m[i] = -1e30f; l[i] = 0.f; o[i][0] = 0.f; o[i][1] = 0.f; }

    int t0 = 0, t1 = SS / 64 - 1;
    const bool masked = (win < SS);
    if (masked) {
        t0 = (i0 - win) >> 6;        if (t0 < 0) t0 = 0;
        t1 = (i0 + 63 + win) >> 6;   if (t1 > SS / 64 - 1) t1 = SS / 64 - 1;
    }
    const float scl = 0.17677669529663688f;  // 1/sqrt(32)

    for (int kt = t0; kt <= t1; kt++) {
        const int k0 = kt * 64;
        __syncthreads();   // protect Ks/Vt/Ps from previous iteration's readers
        // ---- load K tile (row-major) and V tile (transposed) coalesced
        {
            const float* kp = qkv + ((size_t)(b * SS + k0 + lr)) * D3 + DD + h * HD + lc4;
            *(float4*)&Ks[lr][lc4]      = *(const float4*)kp;
            *(float4*)&Ks[lr + 32][lc4] = *(const float4*)(kp + 32 * D3);
            const float* vp = kp + DD;
            float4 v0 = *(const float4*)vp;
            float4 v1 = *(const float4*)(vp + 32 * D3);
            Vt[lc4 + 0][lr] = v0.x; Vt[lc4 + 1][lr] = v0.y;
            Vt[lc4 + 2][lr] = v0.z; Vt[lc4 + 3][lr] = v0.w;
            Vt[lc4 + 0][lr + 32] = v1.x; Vt[lc4 + 1][lr + 32] = v1.y;
            Vt[lc4 + 2][lr + 32] = v1.z; Vt[lc4 + 3][lr + 32] = v1.w;
        }
        __syncthreads();

        // ---- score GEMM: 64x64x32, 4x4 per thread
        float acc[4][4] = {};
        #pragma unroll
        for (int kk = 0; kk < HD; kk += 4) {
            float4 a4[4], b4[4];
            #pragma unroll
            for (int i = 0; i < 4; i++) a4[i] = *(const float4*)&Qs[ty * 4 + i][kk];
            #pragma unroll
            for (int j = 0; j < 4; j++) b4[j] = *(const float4*)&Ks[tx * 4 + j][kk];
            #pragma unroll
            for (int i = 0; i < 4; i++)
                #pragma unroll
                for (int j = 0; j < 4; j++)
                    acc[i][j] += a4[i].x * b4[j].x + a4[i].y * b4[j].y
                               + a4[i].z * b4[j].z + a4[i].w * b4[j].w;
        }
        // scale + band mask
        #pragma unroll
        for (int i = 0; i < 4; i++)
            #pragma unroll
            for (int j = 0; j < 4; j++) {
                float s = acc[i][j] * scl;
                if (masked) {
                    int di = (i0 + ty * 4 + i) - (k0 + tx * 4 + j);
                    if (di > win || di < -win) s = -1e30f;
                }
                acc[i][j] = s;
            }

        // ---- online softmax (per row; 16-lane row-group reductions)
        #pragma unroll
        for (int i = 0; i < 4; i++) {
            float tm = fmaxf(fmaxf(acc[i][0], acc[i][1]), fmaxf(acc[i][2], acc[i][3]));
            #pragma unroll
            for (int off = 1; off < 16; off <<= 1) tm = fmaxf(tm, __shfl_xor(tm, off, 64));
            float mn = fmaxf(m[i], tm);
            float alpha = __expf(m[i] - mn);
            float p0 = __expf(acc[i][0] - mn), p1 = __expf(acc[i][1] - mn);
            float p2 = __expf(acc[i][2] - mn), p3 = __expf(acc[i][3] - mn);
            float ts = p0 + p1 + p2 + p3;
            #pragma unroll
            for (int off = 1; off < 16; off <<= 1) ts += __shfl_xor(ts, off, 64);
            l[i] = l[i] * alpha + ts;
            o[i][0] *= alpha; o[i][1] *= alpha;
            m[i] = mn;
            float4 pv = { p0, p1, p2, p3 };
            *(float4*)&Ps[ty * 4 + i][tx * 4] = pv;
        }
        __syncthreads();

        // ---- PV: o[4][2] += P[64x64] @ V[64x32] slice
        const int d0 = tx * 2;
        #pragma unroll
        for (int j4 = 0; j4 < 64; j4 += 4) {
            float4 va = *(const float4*)&Vt[d0][j4];
            float4 vb = *(const float4*)&Vt[d0 + 1][j4];
            #pragma unroll
            for (int i = 0; i < 4; i++) {
                float4 p = *(const float4*)&Ps[ty * 4 + i][j4];
                o[i][0] += p.x * va.x + p.y * va.y + p.z * va.z + p.w * va.w;
                o[i][1] += p.x * vb.x + p.y * vb.y + p.z * vb.z + p.w * vb.w;
            }
        }
    }

    // ---- write output
    const int d0 = tx * 2;
    #pragma unroll
    for (int i = 0; i < 4; i++) {
        float invl = 1.0f / l[i];
        size_t idx = ((size_t)(b * SS + i0 + ty * 4 + i)) * DD + h * HD + d0;
        float2 ov = { o[i][0] * invl, o[i][1] * invl };
        *(float2*)&out[idx] = ov;
    }
}

// ---------------------------------------------------------------------------
// out = LN(a [+ r]) * g + b   — one block (256 thr) per row, D=256
__global__ __launch_bounds__(256) void ln_kernel(
    const float* __restrict__ a, const float* __restrict__ r,
    const float* __restrict__ g, const float* __restrict__ bt,
    float* __restrict__ outf)
{
    const int row = blockIdx.x, d = threadIdx.x;
    const size_t idx = (size_t)row * DD + d;
    float v = a[idx];
    if (r) v += r[idx];
    const int lane = d & 63, wid = d >> 6;
    float s = v;
    #pragma unroll
    for (int o = 32; o; o >>= 1) s += __shfl_xor(s, o, 64);
    __shared__ float r1[4], r2[4];
    if (lane == 0) r1[wid] = s;
    __syncthreads();
    float mean = (r1[0] + r1[1] + r1[2] + r1[3]) * (1.0f / 256.0f);
    float dv = v - mean;
    float s2 = dv * dv;
    #pragma unroll
    for (int o = 32; o; o >>= 1) s2 += __shfl_xor(s2, o, 64);
    if (lane == 0) r2[wid] = s2;
    __syncthreads();
    float var = (r2[0] + r2[1] + r2[2] + r2[3]) * (1.0f / 256.0f);
    outf[idx] = dv * rsqrtf(var + 1e-5f) * g[d] + bt[d];
}

// ---------------------------------------------------------------------------
extern "C" void kernel_launch(void* const* d_in, const int* in_sizes, int n_in,
                              void* d_out, int out_size, void* d_ws, size_t ws_size,
                              hipStream_t stream)
{
    const float* xin   = (const float*)d_in[0];
    const float* scale = (const float*)d_in[1];
    const float* Win_a = (const float*)d_in[2];
    const float* bin_a = (const float*)d_in[3];
    const float* Wout_a= (const float*)d_in[4];
    const float* bout_a= (const float*)d_in[5];
    const float* Win_e = (const float*)d_in[6];
    const float* bin_e = (const float*)d_in[7];
    const float* Wout_e= (const float*)d_in[8];
    const float* bout_e= (const float*)d_in[9];
    const float* ln1_g = (const float*)d_in[10];
    const float* ln1_b = (const float*)d_in[11];
    const float* ln2_g = (const float*)d_in[12];
    const float* ln2_b = (const float*)d_in[13];
    const float* W1    = (const float*)d_in[14];
    const float* b1    = (const float*)d_in[15];
    const float* W2    = (const float*)d_in[16];
    const float* b2    = (const float*)d_in[17];
    const float* lnf_g = (const float*)d_in[18];
    const float* lnf_b = (const float*)d_in[19];

    float* ws = (float*)d_ws;
    float* X   = ws;                       // 4096*256
    float* X2  = X   + (size_t)NTOK * DD;
    float* P   = X2  + (size_t)NTOK * DD;
    float* AT  = P   + (size_t)NTOK * DD;
    float* QKV = AT  + (size_t)NTOK * DD;  // 4096*768
    float* HML = QKV + (size_t)NTOK * D3;  // 4096*1024

    add_pos_kernel<<<(NTOK * DD + 255) / 256, 256, 0, stream>>>(xin, scale, X, NTOK * DD);

    float* cur = X;
    float* oth = X2;
    for (int l = 0; l < 2; l++) {
        const float* WinA  = Win_a  + (size_t)l * D3 * DD;
        const float* binA  = bin_a  + (size_t)l * D3;
        const float* WoutA = Wout_a + (size_t)l * DD * DD;
        const float* boutA = bout_a + (size_t)l * DD;
        const float* WinE  = Win_e  + (size_t)l * D3 * DD;
        const float* binE  = bin_e  + (size_t)l * D3;
        const float* WoutE = Wout_e + (size_t)l * DD * DD;
        const float* boutE = bout_e + (size_t)l * DD;
        const float* W1l   = W1 + (size_t)l * MLP * DD;
        const float* b1l   = b1 + (size_t)l * MLP;
        const float* W2l   = W2 + (size_t)l * DD * MLP;
        const float* b2l   = b2 + (size_t)l * DD;

        // --- full self-attention
        gemm_bias<<<dim3(D3 / Bb, NTOK / Bb), 256, 0, stream>>>(
            cur, WinA, binA, nullptr, QKV, NTOK, D3, DD, 0);
        attn_tile_kernel<<<dim3(SS / 64, HH, BB), 256, 0, stream>>>(QKV, AT, 1 << 28);
        gemm_bias<<<dim3(DD / Bb, NTOK / Bb), 256, 0, stream>>>(
            AT, WoutA, boutA, nullptr, P, NTOK, DD, DD, 0);
        ln_kernel<<<NTOK, 256, 0, stream>>>(P, cur, ln1_g + l * DD, ln1_b + l * DD, oth);

        // --- banded self-attention (|i-j| <= 64)
        gemm_bias<<<dim3(D3 / Bb, NTOK / Bb), 256, 0, stream>>>(
            oth, WinE, binE, nullptr, QKV, NTOK, D3, DD, 0);
        attn_tile_kernel<<<dim3(SS / 64, HH, BB), 256, 0, stream>>>(QKV, AT, 64);
        gemm_bias<<<dim3(DD / Bb, NTOK / Bb), 256, 0, stream>>>(
            AT, WoutE, boutE, nullptr, P, NTOK, DD, DD, 0);
        ln_kernel<<<NTOK, 256, 0, stream>>>(P, oth, ln2_g + l * DD, ln2_b + l * DD, cur);
        // attended now in cur

        // --- MLP with exact gelu, fused residual
        gemm_bias<<<dim3(MLP / Bb, NTOK / Bb), 256, 0, stream>>>(
            cur, W1l, b1l, nullptr, HML, NTOK, MLP, DD, 1);
        gemm_bias<<<dim3(DD / Bb, NTOK / Bb), 256, 0, stream>>>(
            HML, W2l, b2l, cur, oth, NTOK, DD, MLP, 0);

        float* t = cur; cur = oth; oth = t;   // x for next layer is in cur
    }

    ln_kernel<<<NTOK, 256, 0, stream>>>(cur, nullptr, lnf_g, lnf_b, (float*)d_out);
}

// Round 5
// 822.456 us; speedup vs baseline: 3.8370x; 1.3019x over previous
//
#include <hip/hip_runtime.h>
#include <math.h>

// Problem constants
#define BB 4
#define SS 1024
#define DD 256
#define HH 8
#define HD 32
#define D3 768
#define MLP 1024
#define NTOK (BB * SS)   // 4096

typedef __attribute__((ext_vector_type(8))) short short8;
typedef __attribute__((ext_vector_type(4))) float f32x4;

__device__ __forceinline__ unsigned short f2bfu(float f) {
    union { float f; unsigned i; } u; u.f = f;
    unsigned r = u.i + 0x7fffu + ((u.i >> 16) & 1u);   // RNE
    return (unsigned short)(r >> 16);
}

// ---------------------------------------------------------------------------
// weights fp32 -> bf16 (single kernel over 6 concatenated arrays)
#define W_TOT 2097152
__global__ __launch_bounds__(256) void conv_weights(
    const float* __restrict__ a0, const float* __restrict__ a1,
    const float* __restrict__ a2, const float* __restrict__ a3,
    const float* __restrict__ a4, const float* __restrict__ a5,
    unsigned short* __restrict__ out)
{
    int i = blockIdx.x * 256 + threadIdx.x;
    const float* s; int off;
    if      (i <  393216) { s = a0; off = 0;       }
    else if (i <  524288) { s = a1; off = 393216;  }
    else if (i <  917504) { s = a2; off = 524288;  }
    else if (i < 1048576) { s = a3; off = 917504;  }
    else if (i < 1572864) { s = a4; off = 1048576; }
    else                  { s = a5; off = 1572864; }
    out[i] = f2bfu(s[i - off]);
}

// ---------------------------------------------------------------------------
// x (f32) + positional encoding -> fp32 + bf16
__global__ __launch_bounds__(256) void add_pos_kernel(
    const float* __restrict__ x, const float* __restrict__ scale,
    float* __restrict__ out, unsigned short* __restrict__ outb, int n)
{
    int i = blockIdx.x * 256 + threadIdx.x;
    if (i >= n) return;
    int s = (i >> 8) & (SS - 1);
    float v = x[i] + (float)s * scale[0];
    out[i] = v;
    outb[i] = f2bfu(v);
}

// ---------------------------------------------------------------------------
// fp32 SMEM GEMM (precision path, layer-0 full-attn QKV only):
// C[M,N] = A[M,K](f32) @ W[N,K]^T(f32) + bias(f32)
#define Bb 64
#define BKK 16
__global__ __launch_bounds__(256) void gemm_bias(
    const float* __restrict__ A, const float* __restrict__ W,
    const float* __restrict__ bias, float* __restrict__ C,
    int M, int N, int K)
{
    __shared__ float As[BKK][Bb + 1];
    __shared__ float Ws[BKK][Bb + 1];
    const int tx = threadIdx.x & 15, ty = threadIdx.x >> 4;
    const int m0 = blockIdx.y * Bb, n0 = blockIdx.x * Bb;
    const int lr = threadIdx.x >> 2;
    const int lc = (threadIdx.x & 3) * 4;

    float acc[4][4] = {};
    for (int k0 = 0; k0 < K; k0 += BKK) {
        float4 av = *(const float4*)(A + (size_t)(m0 + lr) * K + k0 + lc);
        As[lc + 0][lr] = av.x; As[lc + 1][lr] = av.y;
        As[lc + 2][lr] = av.z; As[lc + 3][lr] = av.w;
        float4 wv = *(const float4*)(W + (size_t)(n0 + lr) * K + k0 + lc);
        Ws[lc + 0][lr] = wv.x; Ws[lc + 1][lr] = wv.y;
        Ws[lc + 2][lr] = wv.z; Ws[lc + 3][lr] = wv.w;
        __syncthreads();
        #pragma unroll
        for (int kk = 0; kk < BKK; kk++) {
            float a[4], bv[4];
            #pragma unroll
            for (int i = 0; i < 4; i++) a[i] = As[kk][ty * 4 + i];
            #pragma unroll
            for (int j = 0; j < 4; j++) bv[j] = Ws[kk][tx * 4 + j];
            #pragma unroll
            for (int i = 0; i < 4; i++)
                #pragma unroll
                for (int j = 0; j < 4; j++)
                    acc[i][j] += a[i] * bv[j];
        }
        __syncthreads();
    }
    #pragma unroll
    for (int i = 0; i < 4; i++) {
        int row = m0 + ty * 4 + i;
        #pragma unroll
        for (int j = 0; j < 4; j++) {
            int col = n0 + tx * 4 + j;
            C[(size_t)row * N + col] = acc[i][j] + bias[col];
        }
    }
}

// ---------------------------------------------------------------------------
// MFMA GEMM: C[M,N] = A[M,K](bf16) @ W[N,K]^T(bf16) + bias(f32)
//            [+gelu] [+resid f32] -> outf (f32) and/or outb (bf16)
// 128x128 block tile, 256 thr = 4 waves (2x2 of 64x64), BK=32.
#define LDP 40
__global__ __launch_bounds__(256) void gemm_mfma(
    const unsigned short* __restrict__ A, const unsigned short* __restrict__ W,
    const float* __restrict__ bias, const float* __restrict__ resid,
    float* __restrict__ outf, unsigned short* __restrict__ outb,
    int M, int N, int K, int act)
{
    __shared__ __align__(16) unsigned short As[128 * LDP];
    __shared__ __align__(16) unsigned short Bs[128 * LDP];
    const int t = threadIdx.x;
    const int lane = t & 63, wave = t >> 6;
    const int wr = wave >> 1, wc = wave & 1;
    const int m0 = blockIdx.y * 128, n0 = blockIdx.x * 128;
    const int sr = t >> 2;
    const int sc = (t & 3) * 8;

    const unsigned short* Ag = A + (size_t)(m0 + sr) * K + sc;
    const unsigned short* Wg = W + (size_t)(n0 + sr) * K + sc;

    f32x4 acc[4][4];
    #pragma unroll
    for (int i = 0; i < 4; i++)
        #pragma unroll
        for (int j = 0; j < 4; j++)
            acc[i][j] = (f32x4){0.f, 0.f, 0.f, 0.f};

    const int lm = lane & 15, lk = (lane >> 4) * 8;

    for (int k0 = 0; k0 < K; k0 += 32) {
        uint4 a0 = *(const uint4*)(Ag + k0);
        uint4 a1 = *(const uint4*)(Ag + (size_t)64 * K + k0);
        uint4 b0 = *(const uint4*)(Wg + k0);
        uint4 b1 = *(const uint4*)(Wg + (size_t)64 * K + k0);
        __syncthreads();
        *(uint4*)&As[sr * LDP + sc]        = a0;
        *(uint4*)&As[(sr + 64) * LDP + sc] = a1;
        *(uint4*)&Bs[sr * LDP + sc]        = b0;
        *(uint4*)&Bs[(sr + 64) * LDP + sc] = b1;
        __syncthreads();

        short8 af[4], bf[4];
        #pragma unroll
        for (int i = 0; i < 4; i++)
            af[i] = *(const short8*)&As[(wr * 64 + i * 16 + lm) * LDP + lk];
        #pragma unroll
        for (int j = 0; j < 4; j++)
            bf[j] = *(const short8*)&Bs[(wc * 64 + j * 16 + lm) * LDP + lk];
        #pragma unroll
        for (int i = 0; i < 4; i++)
            #pragma unroll
            for (int j = 0; j < 4; j++)
                acc[i][j] = __builtin_amdgcn_mfma_f32_16x16x32_bf16(
                    af[i], bf[j], acc[i][j], 0, 0, 0);
    }

    const int lq = lane >> 4;
    #pragma unroll
    for (int j = 0; j < 4; j++) {
        int col = n0 + wc * 64 + j * 16 + lm;
        float bv = bias[col];
        #pragma unroll
        for (int i = 0; i < 4; i++) {
            #pragma unroll
            for (int r = 0; r < 4; r++) {
                int row = m0 + wr * 64 + i * 16 + lq * 4 + r;
                float v = acc[i][j][r] + bv;
                if (act) v = 0.5f * v * (1.0f + erff(v * 0.70710678118654752f));
                size_t idx = (size_t)row * N + col;
                if (resid) v += resid[idx];
                if (outf) outf[idx] = v;
                if (outb) outb[idx] = f2bfu(v);
            }
        }
    }
}

// ---------------------------------------------------------------------------
// Flash attention, fp32 qkv in (precision path, layer-0 full attn), bf16 out.
__global__ __launch_bounds__(256) void attn_f32_kernel(
    const float* __restrict__ qkv, unsigned short* __restrict__ out, int win)
{
    __shared__ __align__(16) float Qs[64][36];
    __shared__ __align__(16) float Ks[64][36];
    __shared__ __align__(16) float Vt[HD][68];
    __shared__ __align__(16) float Ps[64][68];

    const int t  = threadIdx.x;
    const int tx = t & 15, ty = t >> 4;
    const int i0 = blockIdx.x * 64;
    const int h  = blockIdx.y, b = blockIdx.z;
    const int lr = t >> 3, lc4 = (t & 7) * 4;

    {
        const float* qp = qkv + ((size_t)(b * SS + i0 + lr)) * D3 + h * HD + lc4;
        *(float4*)&Qs[lr][lc4]      = *(const float4*)qp;
        *(float4*)&Qs[lr + 32][lc4] = *(const float4*)(qp + 32 * D3);
    }

    float m[4], l[4], o[4][2];
    #pragma unroll
    for (int i = 0; i < 4; i++) { m[i] = -1e30f; l[i] = 0.f; o[i][0] = 0.f; o[i][1] = 0.f; }

    int t0 = 0, t1 = SS / 64 - 1;
    const bool masked = (win < SS);
    if (masked) {
        t0 = (i0 - win) >> 6;        if (t0 < 0) t0 = 0;
        t1 = (i0 + 63 + win) >> 6;   if (t1 > SS / 64 - 1) t1 = SS / 64 - 1;
    }
    const float scl = 0.17677669529663688f;

    for (int kt = t0; kt <= t1; kt++) {
        const int k0 = kt * 64;
        __syncthreads();
        {
            const float* kp = qkv + ((size_t)(b * SS + k0 + lr)) * D3 + DD + h * HD + lc4;
            *(float4*)&Ks[lr][lc4]      = *(const float4*)kp;
            *(float4*)&Ks[lr + 32][lc4] = *(const float4*)(kp + 32 * D3);
            const float* vp = kp + DD;
            float4 v0 = *(const float4*)vp;
            float4 v1 = *(const float4*)(vp + 32 * D3);
            Vt[lc4 + 0][lr] = v0.x; Vt[lc4 + 1][lr] = v0.y;
            Vt[lc4 + 2][lr] = v0.z; Vt[lc4 + 3][lr] = v0.w;
            Vt[lc4 + 0][lr + 32] = v1.x; Vt[lc4 + 1][lr + 32] = v1.y;
            Vt[lc4 + 2][lr + 32] = v1.z; Vt[lc4 + 3][lr + 32] = v1.w;
        }
        __syncthreads();

        float acc[4][4] = {};
        #pragma unroll
        for (int kk = 0; kk < HD; kk += 4) {
            float4 a4[4], b4[4];
            #pragma unroll
            for (int i = 0; i < 4; i++) a4[i] = *(const float4*)&Qs[ty * 4 + i][kk];
            #pragma unroll
            for (int j = 0; j < 4; j++) b4[j] = *(const float4*)&Ks[tx * 4 + j][kk];
            #pragma unroll
            for (int i = 0; i < 4; i++)
                #pragma unroll
                for (int j = 0; j < 4; j++)
                    acc[i][j] += a4[i].x * b4[j].x + a4[i].y * b4[j].y
                               + a4[i].z * b4[j].z + a4[i].w * b4[j].w;
        }
        #pragma unroll
        for (int i = 0; i < 4; i++)
            #pragma unroll
            for (int j = 0; j < 4; j++) {
                float s = acc[i][j] * scl;
                if (masked) {
                    int di = (i0 + ty * 4 + i) - (k0 + tx * 4 + j);
                    if (di > win || di < -win) s = -1e30f;
                }
                acc[i][j] = s;
            }

        #pragma unroll
        for (int i = 0; i < 4; i++) {
            float tm = fmaxf(fmaxf(acc[i][0], acc[i][1]), fmaxf(acc[i][2], acc[i][3]));
            #pragma unroll
            for (int off = 1; off < 16; off <<= 1) tm = fmaxf(tm, __shfl_xor(tm, off, 64));
            float mn = fmaxf(m[i], tm);
            float alpha = __expf(m[i] - mn);
            float p0 = __expf(acc[i][0] - mn), p1 = __expf(acc[i][1] - mn);
            float p2 = __expf(acc[i][2] - mn), p3 = __expf(acc[i][3] - mn);
            float ts = p0 + p1 + p2 + p3;
            #pragma unroll
            for (int off = 1; off < 16; off <<= 1) ts += __shfl_xor(ts, off, 64);
            l[i] = l[i] * alpha + ts;
            o[i][0] *= alpha; o[i][1] *= alpha;
            m[i] = mn;
            float4 pv = { p0, p1, p2, p3 };
            *(float4*)&Ps[ty * 4 + i][tx * 4] = pv;
        }
        __syncthreads();

        const int d0 = tx * 2;
        #pragma unroll
        for (int j4 = 0; j4 < 64; j4 += 4) {
            float4 va = *(const float4*)&Vt[d0][j4];
            float4 vb = *(const float4*)&Vt[d0 + 1][j4];
            #pragma unroll
            for (int i = 0; i < 4; i++) {
                float4 p = *(const float4*)&Ps[ty * 4 + i][j4];
                o[i][0] += p.x * va.x + p.y * va.y + p.z * va.z + p.w * va.w;
                o[i][1] += p.x * vb.x + p.y * vb.y + p.z * vb.z + p.w * vb.w;
            }
        }
    }

    const int d0 = tx * 2;
    #pragma unroll
    for (int i = 0; i < 4; i++) {
        float invl = 1.0f / l[i];
        size_t idx = ((size_t)(b * SS + i0 + ty * 4 + i)) * DD + h * HD + d0;
        unsigned pw = ((unsigned)f2bfu(o[i][1] * invl) << 16) | f2bfu(o[i][0] * invl);
        *(unsigned*)&out[idx] = pw;
    }
}

// ---------------------------------------------------------------------------
// Flash attention, bf16 qkv in, bf16 out (post-LN inputs are O(1) -> safe).
__global__ __launch_bounds__(256) void attn_bf16_kernel(
    const unsigned short* __restrict__ qkv, unsigned short* __restrict__ out, int win)
{
    __shared__ __align__(16) float Qs[64][36];
    __shared__ __align__(16) float Ks[64][36];
    __shared__ __align__(16) float Vt[HD][68];
    __shared__ __align__(16) float Ps[64][68];

    const int t  = threadIdx.x;
    const int tx = t & 15, ty = t >> 4;
    const int i0 = blockIdx.x * 64;
    const int h  = blockIdx.y, b = blockIdx.z;
    const int row  = t >> 2;
    const int col8 = (t & 3) * 8;

    {
        const unsigned short* qp =
            qkv + ((size_t)(b * SS + i0 + row)) * D3 + h * HD + col8;
        uint4 qv = *(const uint4*)qp;
        unsigned u[4] = { qv.x, qv.y, qv.z, qv.w };
        #pragma unroll
        for (int c = 0; c < 4; c++) {
            union { unsigned i; float f; } lo, hi;
            lo.i = u[c] << 16; hi.i = u[c] & 0xffff0000u;
            Qs[row][col8 + 2 * c]     = lo.f;
            Qs[row][col8 + 2 * c + 1] = hi.f;
        }
    }

    float m[4], l[4], o[4][2];
    #pragma unroll
    for (int i = 0; i < 4; i++) { m[i] = -1e30f; l[i] = 0.f; o[i][0] = 0.f; o[i][1] = 0.f; }

    int t0 = 0, t1 = SS / 64 - 1;
    const bool masked = (win < SS);
    if (masked) {
        t0 = (i0 - win) >> 6;        if (t0 < 0) t0 = 0;
        t1 = (i0 + 63 + win) >> 6;   if (t1 > SS / 64 - 1) t1 = SS / 64 - 1;
    }
    const float scl = 0.17677669529663688f;

    for (int kt = t0; kt <= t1; kt++) {
        const int k0 = kt * 64;
        __syncthreads();
        {
            const unsigned short* kp =
                qkv + ((size_t)(b * SS + k0 + row)) * D3 + DD + h * HD + col8;
            uint4 kv = *(const uint4*)kp;
            unsigned u[4] = { kv.x, kv.y, kv.z, kv.w };
            #pragma unroll
            for (int c = 0; c < 4; c++) {
                union { unsigned i; float f; } lo, hi;
                lo.i = u[c] << 16; hi.i = u[c] & 0xffff0000u;
                Ks[row][col8 + 2 * c]     = lo.f;
                Ks[row][col8 + 2 * c + 1] = hi.f;
            }
            uint4 vv = *(const uint4*)(kp + DD);
            unsigned w[4] = { vv.x, vv.y, vv.z, vv.w };
            #pragma unroll
            for (int c = 0; c < 4; c++) {
                union { unsigned i; float f; } lo, hi;
                lo.i = w[c] << 16; hi.i = w[c] & 0xffff0000u;
                Vt[col8 + 2 * c][row]     = lo.f;
                Vt[col8 + 2 * c + 1][row] = hi.f;
            }
        }
        __syncthreads();

        float acc[4][4] = {};
        #pragma unroll
        for (int kk = 0; kk < HD; kk += 4) {
            float4 a4[4], b4[4];
            #pragma unroll
            for (int i = 0; i < 4; i++) a4[i] = *(const float4*)&Qs[ty * 4 + i][kk];
            #pragma unroll
            for (int j = 0; j < 4; j++) b4[j] = *(const float4*)&Ks[tx * 4 + j][kk];
            #pragma unroll
            for (int i = 0; i < 4; i++)
                #pragma unroll
                for (int j = 0; j < 4; j++)
                    acc[i][j] += a4[i].x * b4[j].x + a4[i].y * b4[j].y
                               + a4[i].z * b4[j].z + a4[i].w * b4[j].w;
        }
        #pragma unroll
        for (int i = 0; i < 4; i++)
            #pragma unroll
            for (int j = 0; j < 4; j++) {
                float s = acc[i][j] * scl;
                if (masked) {
                    int di = (i0 + ty * 4 + i) - (k0 + tx * 4 + j);
                    if (di > win || di < -win) s = -1e30f;
                }
                acc[i][j] = s;
            }

        #pragma unroll
        for (int i = 0; i < 4; i++) {
            float tm = fmaxf(fmaxf(acc[i][0], acc[i][1]), fmaxf(acc[i][2], acc[i][3]));
            #pragma unroll
            for (int off = 1; off < 16; off <<= 1) tm = fmaxf(tm, __shfl_xor(tm, off, 64));
            float mn = fmaxf(m[i], tm);
            float alpha = __expf(m[i] - mn);
            float p0 = __expf(acc[i][0] - mn), p1 = __expf(acc[i][1] - mn);
            float p2 = __expf(acc[i][2] - mn), p3 = __expf(acc[i][3] - mn);
            float ts = p0 + p1 + p2 + p3;
            #pragma unroll
            for (int off = 1; off < 16; off <<= 1) ts += __shfl_xor(ts, off, 64);
            l[i] = l[i] * alpha + ts;
            o[i][0] *= alpha; o[i][1] *= alpha;
            m[i] = mn;
            float4 pv = { p0, p1, p2, p3 };
            *(float4*)&Ps[ty * 4 + i][tx * 4] = pv;
        }
        __syncthreads();

        const int d0 = tx * 2;
        #pragma unroll
        for (int j4 = 0; j4 < 64; j4 += 4) {
            float4 va = *(const float4*)&Vt[d0][j4];
            float4 vb = *(const float4*)&Vt[d0 + 1][j4];
            #pragma unroll
            for (int i = 0; i < 4; i++) {
                float4 p = *(const float4*)&Ps[ty * 4 + i][j4];
                o[i][0] += p.x * va.x + p.y * va.y + p.z * va.z + p.w * va.w;
                o[i][1] += p.x * vb.x + p.y * vb.y + p.z * vb.z + p.w * vb.w;
            }
        }
    }

    const int d0 = tx * 2;
    #pragma unroll
    for (int i = 0; i < 4; i++) {
        float invl = 1.0f / l[i];
        size_t idx = ((size_t)(b * SS + i0 + ty * 4 + i)) * DD + h * HD + d0;
        unsigned pw = ((unsigned)f2bfu(o[i][1] * invl) << 16) | f2bfu(o[i][0] * invl);
        *(unsigned*)&out[idx] = pw;
    }
}

// ---------------------------------------------------------------------------
// out = LN(a [+ r]) * g + b   — one block (256 thr) per row, D=256
__global__ __launch_bounds__(256) void ln_kernel(
    const float* __restrict__ a, const float* __restrict__ r,
    const float* __restrict__ g, const float* __restrict__ bt,
    float* __restrict__ outf, unsigned short* __restrict__ outb)
{
    const int row = blockIdx.x, d = threadIdx.x;
    const size_t idx = (size_t)row * DD + d;
    float v = a[idx];
    if (r) v += r[idx];
    const int lane = d & 63, wid = d >> 6;
    float s = v;
    #pragma unroll
    for (int o = 32; o; o >>= 1) s += __shfl_xor(s, o, 64);
    __shared__ float r1[4], r2[4];
    if (lane == 0) r1[wid] = s;
    __syncthreads();
    float mean = (r1[0] + r1[1] + r1[2] + r1[3]) * (1.0f / 256.0f);
    float dv = v - mean;
    float s2 = dv * dv;
    #pragma unroll
    for (int o = 32; o; o >>= 1) s2 += __shfl_xor(s2, o, 64);
    if (lane == 0) r2[wid] = s2;
    __syncthreads();
    float var = (r2[0] + r2[1] + r2[2] + r2[3]) * (1.0f / 256.0f);
    float outv = dv * rsqrtf(var + 1e-5f) * g[d] + bt[d];
    if (outf) outf[idx] = outv;
    if (outb) outb[idx] = f2bfu(outv);
}

// ---------------------------------------------------------------------------
extern "C" void kernel_launch(void* const* d_in, const int* in_sizes, int n_in,
                              void* d_out, int out_size, void* d_ws, size_t ws_size,
                              hipStream_t stream)
{
    const float* xin   = (const float*)d_in[0];
    const float* scale = (const float*)d_in[1];
    const float* Win_a = (const float*)d_in[2];
    const float* bin_a = (const float*)d_in[3];
    const float* Wout_a= (const float*)d_in[4];
    const float* bout_a= (const float*)d_in[5];
    const float* Win_e = (const float*)d_in[6];
    const float* bin_e = (const float*)d_in[7];
    const float* Wout_e= (const float*)d_in[8];
    const float* bout_e= (const float*)d_in[9];
    const float* ln1_g = (const float*)d_in[10];
    const float* ln1_b = (const float*)d_in[11];
    const float* ln2_g = (const float*)d_in[12];
    const float* ln2_b = (const float*)d_in[13];
    const float* W1    = (const float*)d_in[14];
    const float* b1    = (const float*)d_in[15];
    const float* W2    = (const float*)d_in[16];
    const float* b2    = (const float*)d_in[17];
    const float* lnf_g = (const float*)d_in[18];
    const float* lnf_b = (const float*)d_in[19];

    char* ws = (char*)d_ws;
    float* X    = (float*)ws;                     ws += (size_t)NTOK * DD * 4;
    float* X2   = (float*)ws;                     ws += (size_t)NTOK * DD * 4;
    float* P    = (float*)ws;                     ws += (size_t)NTOK * DD * 4;
    float* QKVf = (float*)ws;                     ws += (size_t)NTOK * D3 * 4;
    unsigned short* Xb   = (unsigned short*)ws;   ws += (size_t)NTOK * DD * 2;
    unsigned short* X2b  = (unsigned short*)ws;   ws += (size_t)NTOK * DD * 2;
    unsigned short* ATb  = (unsigned short*)ws;   ws += (size_t)NTOK * DD * 2;
    unsigned short* QKVb = (unsigned short*)ws;   ws += (size_t)NTOK * D3 * 2;
    unsigned short* HMLb = (unsigned short*)ws;   ws += (size_t)NTOK * MLP * 2;
    unsigned short* Wb   = (unsigned short*)ws;   ws += (size_t)W_TOT * 2;

    unsigned short* WinA_b  = Wb + 0;
    unsigned short* WoutA_b = Wb + 393216;
    unsigned short* WinE_b  = Wb + 524288;
    unsigned short* WoutE_b = Wb + 917504;
    unsigned short* W1_b    = Wb + 1048576;
    unsigned short* W2_b    = Wb + 1572864;

    conv_weights<<<W_TOT / 256, 256, 0, stream>>>(
        Win_a, Wout_a, Win_e, Wout_e, W1, W2, Wb);
    add_pos_kernel<<<(NTOK * DD + 255) / 256, 256, 0, stream>>>(
        xin, scale, X, Xb, NTOK * DD);

    float* cur = X;            float* oth = X2;
    unsigned short* curb = Xb; unsigned short* othb = X2b;

    for (int l = 0; l < 2; l++) {
        // --- full self-attention
        if (l == 0) {
            // precision path: pos-ramp makes scores O(100s); bf16 flips argmax
            gemm_bias<<<dim3(D3 / Bb, NTOK / Bb), 256, 0, stream>>>(
                cur, Win_a, bin_a, QKVf, NTOK, D3, DD);
            attn_f32_kernel<<<dim3(SS / 64, HH, BB), 256, 0, stream>>>(
                QKVf, ATb, 1 << 28);
        } else {
            gemm_mfma<<<dim3(D3 / 128, NTOK / 128), 256, 0, stream>>>(
                curb, WinA_b + (size_t)l * D3 * DD, bin_a + (size_t)l * D3,
                nullptr, nullptr, QKVb, NTOK, D3, DD, 0);
            attn_bf16_kernel<<<dim3(SS / 64, HH, BB), 256, 0, stream>>>(
                QKVb, ATb, 1 << 28);
        }
        gemm_mfma<<<dim3(DD / 128, NTOK / 128), 256, 0, stream>>>(
            ATb, WoutA_b + (size_t)l * DD * DD, bout_a + (size_t)l * DD,
            nullptr, P, nullptr, NTOK, DD, DD, 0);
        ln_kernel<<<NTOK, 256, 0, stream>>>(
            P, cur, ln1_g + l * DD, ln1_b + l * DD, oth, othb);

        // --- banded self-attention (|i-j| <= 64) — post-LN input, bf16-safe
        gemm_mfma<<<dim3(D3 / 128, NTOK / 128), 256, 0, stream>>>(
            othb, WinE_b + (size_t)l * D3 * DD, bin_e + (size_t)l * D3,
            nullptr, nullptr, QKVb, NTOK, D3, DD, 0);
        attn_bf16_kernel<<<dim3(SS / 64, HH, BB), 256, 0, stream>>>(QKVb, ATb, 64);
        gemm_mfma<<<dim3(DD / 128, NTOK / 128), 256, 0, stream>>>(
            ATb, WoutE_b + (size_t)l * DD * DD, bout_e + (size_t)l * DD,
            nullptr, P, nullptr, NTOK, DD, DD, 0);
        ln_kernel<<<NTOK, 256, 0, stream>>>(
            P, oth, ln2_g + l * DD, ln2_b + l * DD, cur, curb);
        // attended now in cur/curb

        // --- MLP with exact gelu, fused residual
        gemm_mfma<<<dim3(MLP / 128, NTOK / 128), 256, 0, stream>>>(
            curb, W1_b + (size_t)l * MLP * DD, b1 + (size_t)l * MLP,
            nullptr, nullptr, HMLb, NTOK, MLP, DD, 1);
        gemm_mfma<<<dim3(DD / 128, NTOK / 128), 256, 0, stream>>>(
            HMLb, W2_b + (size_t)l * DD * MLP, b2 + (size_t)l * DD,
            cur, oth, othb, NTOK, DD, MLP, 0);

        float* tf = cur; cur = oth; oth = tf;
        unsigned short* tb = curb; curb = othb; othb = tb;
    }

    ln_kernel<<<NTOK, 256, 0, stream>>>(cur, nullptr, lnf_g, lnf_b,
                                        (float*)d_out, nullptr);
}

// Round 6
// 444.170 us; speedup vs baseline: 7.1049x; 1.8517x over previous
//
#include <hip/hip_runtime.h>
#include <math.h>

// Problem constants
#define BB 4
#define SS 1024
#define DD 256
#define HH 8
#define HD 32
#define D3 768
#define MLP 1024
#define NTOK (BB * SS)   // 4096

typedef __attribute__((ext_vector_type(8))) short short8;
typedef __attribute__((ext_vector_type(4))) float f32x4;

__device__ __forceinline__ unsigned short f2bfu(float f) {
    union { float f; unsigned i; } u; u.f = f;
    unsigned r = u.i + 0x7fffu + ((u.i >> 16) & 1u);   // RNE
    return (unsigned short)(r >> 16);
}
__device__ __forceinline__ float bfu2f(unsigned short h) {
    union { unsigned i; float f; } u; u.i = ((unsigned)h) << 16; return u.f;
}

// ---------------------------------------------------------------------------
// weights fp32 -> bf16; also lo-part for Win_a layer 0 (hi/lo split path)
#define W_TOT 2097152
#define WL0   196608   // 768*256 = Win_a layer 0
__global__ __launch_bounds__(256) void conv_weights(
    const float* __restrict__ a0, const float* __restrict__ a1,
    const float* __restrict__ a2, const float* __restrict__ a3,
    const float* __restrict__ a4, const float* __restrict__ a5,
    unsigned short* __restrict__ out, unsigned short* __restrict__ out_lo)
{
    int i = blockIdx.x * 256 + threadIdx.x;
    const float* s; int off;
    if      (i <  393216) { s = a0; off = 0;       }
    else if (i <  524288) { s = a1; off = 393216;  }
    else if (i <  917504) { s = a2; off = 524288;  }
    else if (i < 1048576) { s = a3; off = 917504;  }
    else if (i < 1572864) { s = a4; off = 1048576; }
    else                  { s = a5; off = 1572864; }
    float v = s[i - off];
    unsigned short h = f2bfu(v);
    out[i] = h;
    if (i < WL0) out_lo[i] = f2bfu(v - bfu2f(h));
}

// ---------------------------------------------------------------------------
// x (f32) + positional encoding -> fp32 + bf16 hi + bf16 lo
__global__ __launch_bounds__(256) void add_pos_kernel(
    const float* __restrict__ x, const float* __restrict__ scale,
    float* __restrict__ out, unsigned short* __restrict__ outh,
    unsigned short* __restrict__ outl, int n)
{
    int i = blockIdx.x * 256 + threadIdx.x;
    if (i >= n) return;
    int s = (i >> 8) & (SS - 1);
    float v = x[i] + (float)s * scale[0];
    out[i] = v;
    unsigned short h = f2bfu(v);
    outh[i] = h;
    outl[i] = f2bfu(v - bfu2f(h));
}

// ---------------------------------------------------------------------------
// MFMA GEMM: C[M,N] = A[M,K](bf16) @ W[N,K]^T(bf16) + bias(f32)
//            [+gelu] [+resid f32] -> outf (f32) and/or outb (bf16)
// 128x128 block tile, 256 thr = 4 waves (2x2 of 64x64), BK=32.
#define LDP 40
__global__ __launch_bounds__(256) void gemm_mfma(
    const unsigned short* __restrict__ A, const unsigned short* __restrict__ W,
    const float* __restrict__ bias, const float* __restrict__ resid,
    float* __restrict__ outf, unsigned short* __restrict__ outb,
    int M, int N, int K, int act)
{
    __shared__ __align__(16) unsigned short As[128 * LDP];
    __shared__ __align__(16) unsigned short Bs[128 * LDP];
    const int t = threadIdx.x;
    const int lane = t & 63, wave = t >> 6;
    const int wr = wave >> 1, wc = wave & 1;
    const int m0 = blockIdx.y * 128, n0 = blockIdx.x * 128;
    const int sr = t >> 2;
    const int sc = (t & 3) * 8;

    const unsigned short* Ag = A + (size_t)(m0 + sr) * K + sc;
    const unsigned short* Wg = W + (size_t)(n0 + sr) * K + sc;

    f32x4 acc[4][4];
    #pragma unroll
    for (int i = 0; i < 4; i++)
        #pragma unroll
        for (int j = 0; j < 4; j++)
            acc[i][j] = (f32x4){0.f, 0.f, 0.f, 0.f};

    const int lm = lane & 15, lk = (lane >> 4) * 8;

    for (int k0 = 0; k0 < K; k0 += 32) {
        uint4 a0 = *(const uint4*)(Ag + k0);
        uint4 a1 = *(const uint4*)(Ag + (size_t)64 * K + k0);
        uint4 b0 = *(const uint4*)(Wg + k0);
        uint4 b1 = *(const uint4*)(Wg + (size_t)64 * K + k0);
        __syncthreads();
        *(uint4*)&As[sr * LDP + sc]        = a0;
        *(uint4*)&As[(sr + 64) * LDP + sc] = a1;
        *(uint4*)&Bs[sr * LDP + sc]        = b0;
        *(uint4*)&Bs[(sr + 64) * LDP + sc] = b1;
        __syncthreads();

        short8 af[4], bf[4];
        #pragma unroll
        for (int i = 0; i < 4; i++)
            af[i] = *(const short8*)&As[(wr * 64 + i * 16 + lm) * LDP + lk];
        #pragma unroll
        for (int j = 0; j < 4; j++)
            bf[j] = *(const short8*)&Bs[(wc * 64 + j * 16 + lm) * LDP + lk];
        #pragma unroll
        for (int i = 0; i < 4; i++)
            #pragma unroll
            for (int j = 0; j < 4; j++)
                acc[i][j] = __builtin_amdgcn_mfma_f32_16x16x32_bf16(
                    af[i], bf[j], acc[i][j], 0, 0, 0);
    }

    const int lq = lane >> 4;
    #pragma unroll
    for (int j = 0; j < 4; j++) {
        int col = n0 + wc * 64 + j * 16 + lm;
        float bv = bias[col];
        #pragma unroll
        for (int i = 0; i < 4; i++) {
            #pragma unroll
            for (int r = 0; r < 4; r++) {
                int row = m0 + wr * 64 + i * 16 + lq * 4 + r;
                float v = acc[i][j][r] + bv;
                if (act) v = 0.5f * v * (1.0f + erff(v * 0.70710678118654752f));
                size_t idx = (size_t)row * N + col;
                if (resid) v += resid[idx];
                if (outf) outf[idx] = v;
                if (outb) outb[idx] = f2bfu(v);
            }
        }
    }
}

// ---------------------------------------------------------------------------
// Split (hi/lo bf16 ~ fp32) MFMA GEMM for the layer-0 QKV projection:
// C = (Ah+Al)(Wh+Wl)^T + bias ~= Ah Wh + Ah Wl + Al Wh. Outputs hi/lo bf16.
__global__ __launch_bounds__(256) void gemm_mfma_split(
    const unsigned short* __restrict__ Ah, const unsigned short* __restrict__ Al,
    const unsigned short* __restrict__ Wh, const unsigned short* __restrict__ Wl,
    const float* __restrict__ bias,
    unsigned short* __restrict__ outh, unsigned short* __restrict__ outl,
    int M, int N, int K)
{
    __shared__ __align__(16) unsigned short Ash[128 * LDP];
    __shared__ __align__(16) unsigned short Asl[128 * LDP];
    __shared__ __align__(16) unsigned short Bsh[128 * LDP];
    __shared__ __align__(16) unsigned short Bsl[128 * LDP];
    const int t = threadIdx.x;
    const int lane = t & 63, wave = t >> 6;
    const int wr = wave >> 1, wc = wave & 1;
    const int m0 = blockIdx.y * 128, n0 = blockIdx.x * 128;
    const int sr = t >> 2;
    const int sc = (t & 3) * 8;

    const size_t oA = (size_t)(m0 + sr) * K + sc;
    const size_t oW = (size_t)(n0 + sr) * K + sc;

    f32x4 acc[4][4];
    #pragma unroll
    for (int i = 0; i < 4; i++)
        #pragma unroll
        for (int j = 0; j < 4; j++)
            acc[i][j] = (f32x4){0.f, 0.f, 0.f, 0.f};

    const int lm = lane & 15, lk = (lane >> 4) * 8;

    for (int k0 = 0; k0 < K; k0 += 32) {
        uint4 ah0 = *(const uint4*)(Ah + oA + k0);
        uint4 ah1 = *(const uint4*)(Ah + oA + (size_t)64 * K + k0);
        uint4 al0 = *(const uint4*)(Al + oA + k0);
        uint4 al1 = *(const uint4*)(Al + oA + (size_t)64 * K + k0);
        uint4 bh0 = *(const uint4*)(Wh + oW + k0);
        uint4 bh1 = *(const uint4*)(Wh + oW + (size_t)64 * K + k0);
        uint4 bl0 = *(const uint4*)(Wl + oW + k0);
        uint4 bl1 = *(const uint4*)(Wl + oW + (size_t)64 * K + k0);
        __syncthreads();
        *(uint4*)&Ash[sr * LDP + sc]        = ah0;
        *(uint4*)&Ash[(sr + 64) * LDP + sc] = ah1;
        *(uint4*)&Asl[sr * LDP + sc]        = al0;
        *(uint4*)&Asl[(sr + 64) * LDP + sc] = al1;
        *(uint4*)&Bsh[sr * LDP + sc]        = bh0;
        *(uint4*)&Bsh[(sr + 64) * LDP + sc] = bh1;
        *(uint4*)&Bsl[sr * LDP + sc]        = bl0;
        *(uint4*)&Bsl[(sr + 64) * LDP + sc] = bl1;
        __syncthreads();

        short8 afh[4], afl[4], bfh[4], bfl[4];
        #pragma unroll
        for (int i = 0; i < 4; i++) {
            afh[i] = *(const short8*)&Ash[(wr * 64 + i * 16 + lm) * LDP + lk];
            afl[i] = *(const short8*)&Asl[(wr * 64 + i * 16 + lm) * LDP + lk];
        }
        #pragma unroll
        for (int j = 0; j < 4; j++) {
            bfh[j] = *(const short8*)&Bsh[(wc * 64 + j * 16 + lm) * LDP + lk];
            bfl[j] = *(const short8*)&Bsl[(wc * 64 + j * 16 + lm) * LDP + lk];
        }
        #pragma unroll
        for (int i = 0; i < 4; i++)
            #pragma unroll
            for (int j = 0; j < 4; j++) {
                acc[i][j] = __builtin_amdgcn_mfma_f32_16x16x32_bf16(
                    afl[i], bfh[j], acc[i][j], 0, 0, 0);
                acc[i][j] = __builtin_amdgcn_mfma_f32_16x16x32_bf16(
                    afh[i], bfl[j], acc[i][j], 0, 0, 0);
                acc[i][j] = __builtin_amdgcn_mfma_f32_16x16x32_bf16(
                    afh[i], bfh[j], acc[i][j], 0, 0, 0);
            }
    }

    const int lq = lane >> 4;
    #pragma unroll
    for (int j = 0; j < 4; j++) {
        int col = n0 + wc * 64 + j * 16 + lm;
        float bv = bias[col];
        #pragma unroll
        for (int i = 0; i < 4; i++) {
            #pragma unroll
            for (int r = 0; r < 4; r++) {
                int row = m0 + wr * 64 + i * 16 + lq * 4 + r;
                float v = acc[i][j][r] + bv;
                size_t idx = (size_t)row * N + col;
                unsigned short h = f2bfu(v);
                outh[idx] = h;
                outl[idx] = f2bfu(v - bfu2f(h));
            }
        }
    }
}

// ---------------------------------------------------------------------------
// MFMA flash attention. Block = 256 thr (4 waves) per (b, h, 64-q-tile).
// Wave w owns q rows [i0+16w, i0+16w+16). qkv packed (B,S,3D) bf16 (hi; +lo
// when SPLIT for the layer-0 precision path). win >= S -> full attention.
template<bool SPLIT>
__global__ __launch_bounds__(256) void attn_mfma(
    const unsigned short* __restrict__ qkvh,
    const unsigned short* __restrict__ qkvl,
    unsigned short* __restrict__ out, int win)
{
    __shared__ __align__(16) unsigned short Ks [64 * 40];
    __shared__ __align__(16) unsigned short Vt [32 * 72];
    __shared__ __align__(16) unsigned short Ps [64 * 72];
    __shared__ __align__(16) unsigned short Ksl[SPLIT ? 64 * 40 : 8];
    __shared__ __align__(16) unsigned short Vtl[SPLIT ? 32 * 72 : 8];

    const int t = threadIdx.x;
    const int wave = t >> 6, lane = t & 63;
    const int lm = lane & 15, quad = lane >> 4;
    const int i0 = blockIdx.x * 64, h = blockIdx.y, b = blockIdx.z;
    const int sr = t >> 2, sc8 = (t & 3) * 8;

    // Q A-fragments straight from global: A[m=lm][k=quad*8+j]
    const size_t qoff = ((size_t)(b * SS) + i0 + 16 * wave + lm) * D3 + h * HD + quad * 8;
    short8 qh = *(const short8*)(qkvh + qoff);
    short8 ql = {};
    if constexpr (SPLIT) ql = *(const short8*)(qkvl + qoff);

    float m[4], l[4];
    f32x4 o[2];
    #pragma unroll
    for (int r = 0; r < 4; r++) { m[r] = -1e30f; l[r] = 0.f; }
    o[0] = (f32x4){0.f, 0.f, 0.f, 0.f};
    o[1] = (f32x4){0.f, 0.f, 0.f, 0.f};

    int t0 = 0, t1 = SS / 64 - 1;
    const bool masked = (win < SS);
    if (masked) {
        t0 = (i0 - win) >> 6;        if (t0 < 0) t0 = 0;
        t1 = (i0 + 63 + win) >> 6;   if (t1 > SS / 64 - 1) t1 = SS / 64 - 1;
    }
    const float scl = 0.17677669529663688f;  // 1/sqrt(32)

    for (int kt = t0; kt <= t1; kt++) {
        const int k0 = kt * 64;
        __syncthreads();   // all waves done reading Ks/Vt of previous tile
        {
            const size_t koff = ((size_t)(b * SS) + k0 + sr) * D3 + DD + h * HD + sc8;
            short8 kv = *(const short8*)(qkvh + koff);
            *(short8*)&Ks[sr * 40 + sc8] = kv;
            short8 vv = *(const short8*)(qkvh + koff + DD);
            #pragma unroll
            for (int c = 0; c < 8; c++)
                Vt[(sc8 + c) * 72 + sr] = ((unsigned short*)&vv)[c];
            if constexpr (SPLIT) {
                short8 kl = *(const short8*)(qkvl + koff);
                *(short8*)&Ksl[sr * 40 + sc8] = kl;
                short8 vl = *(const short8*)(qkvl + koff + DD);
                #pragma unroll
                for (int c = 0; c < 8; c++)
                    Vtl[(sc8 + c) * 72 + sr] = ((unsigned short*)&vl)[c];
            }
        }
        __syncthreads();

        // ---- scores: 4 MFMAs (x3 terms when SPLIT); C: col=16cb+lm, row=quad*4+r
        f32x4 s[4];
        #pragma unroll
        for (int cb = 0; cb < 4; cb++) {
            short8 kf = *(const short8*)&Ks[(16 * cb + lm) * 40 + quad * 8];
            f32x4 a = (f32x4){0.f, 0.f, 0.f, 0.f};
            if constexpr (SPLIT) {
                short8 kfl = *(const short8*)&Ksl[(16 * cb + lm) * 40 + quad * 8];
                a = __builtin_amdgcn_mfma_f32_16x16x32_bf16(ql, kf,  a, 0, 0, 0);
                a = __builtin_amdgcn_mfma_f32_16x16x32_bf16(qh, kfl, a, 0, 0, 0);
            }
            a = __builtin_amdgcn_mfma_f32_16x16x32_bf16(qh, kf, a, 0, 0, 0);
            s[cb] = a;
        }

        float sc[4][4];
        #pragma unroll
        for (int cb = 0; cb < 4; cb++)
            #pragma unroll
            for (int r = 0; r < 4; r++) {
                float v = s[cb][r] * scl;
                if (masked) {
                    int di = (i0 + 16 * wave + quad * 4 + r) - (k0 + 16 * cb + lm);
                    if (di > win || di < -win) v = -1e30f;
                }
                sc[cb][r] = v;
            }

        // ---- online softmax per row (16-lane quad-group reductions)
        #pragma unroll
        for (int r = 0; r < 4; r++) {
            float tm = fmaxf(fmaxf(sc[0][r], sc[1][r]), fmaxf(sc[2][r], sc[3][r]));
            tm = fmaxf(tm, __shfl_xor(tm, 1, 64));
            tm = fmaxf(tm, __shfl_xor(tm, 2, 64));
            tm = fmaxf(tm, __shfl_xor(tm, 4, 64));
            tm = fmaxf(tm, __shfl_xor(tm, 8, 64));
            float mn = fmaxf(m[r], tm);
            float alpha = __expf(m[r] - mn);
            float p0 = __expf(sc[0][r] - mn), p1 = __expf(sc[1][r] - mn);
            float p2 = __expf(sc[2][r] - mn), p3 = __expf(sc[3][r] - mn);
            float ps = p0 + p1 + p2 + p3;
            ps += __shfl_xor(ps, 1, 64);
            ps += __shfl_xor(ps, 2, 64);
            ps += __shfl_xor(ps, 4, 64);
            ps += __shfl_xor(ps, 8, 64);
            l[r] = l[r] * alpha + ps;
            o[0][r] *= alpha;
            o[1][r] *= alpha;
            m[r] = mn;
            const int pr = (16 * wave + quad * 4 + r) * 72 + lm;
            Ps[pr +  0] = f2bfu(p0);
            Ps[pr + 16] = f2bfu(p1);
            Ps[pr + 32] = f2bfu(p2);
            Ps[pr + 48] = f2bfu(p3);
        }
        // Ps region is wave-private (wave reads only its own 16 rows) — no barrier

        // ---- PV: o[16x32] += P[16x64] @ V[64x32]
        #pragma unroll
        for (int kc = 0; kc < 2; kc++) {
            short8 pf = *(const short8*)&Ps[(16 * wave + lm) * 72 + 32 * kc + quad * 8];
            #pragma unroll
            for (int nh = 0; nh < 2; nh++) {
                short8 vf = *(const short8*)&Vt[(16 * nh + lm) * 72 + 32 * kc + quad * 8];
                o[nh] = __builtin_amdgcn_mfma_f32_16x16x32_bf16(pf, vf, o[nh], 0, 0, 0);
                if constexpr (SPLIT) {
                    short8 vfl = *(const short8*)&Vtl[(16 * nh + lm) * 72 + 32 * kc + quad * 8];
                    o[nh] = __builtin_amdgcn_mfma_f32_16x16x32_bf16(pf, vfl, o[nh], 0, 0, 0);
                }
            }
        }
    }

    // ---- write output: row = i0+16w+quad*4+r, col = h*HD + 16nh + lm
    #pragma unroll
    for (int r = 0; r < 4; r++) {
        float invl = 1.0f / l[r];
        size_t base = ((size_t)(b * SS) + i0 + 16 * wave + quad * 4 + r) * DD + h * HD + lm;
        out[base]      = f2bfu(o[0][r] * invl);
        out[base + 16] = f2bfu(o[1][r] * invl);
    }
}

// ---------------------------------------------------------------------------
// out = LN(a [+ r]) * g + b   — one block (256 thr) per row, D=256
__global__ __launch_bounds__(256) void ln_kernel(
    const float* __restrict__ a, const float* __restrict__ r,
    const float* __restrict__ g, const float* __restrict__ bt,
    float* __restrict__ outf, unsigned short* __restrict__ outb)
{
    const int row = blockIdx.x, d = threadIdx.x;
    const size_t idx = (size_t)row * DD + d;
    float v = a[idx];
    if (r) v += r[idx];
    const int lane = d & 63, wid = d >> 6;
    float s = v;
    #pragma unroll
    for (int o = 32; o; o >>= 1) s += __shfl_xor(s, o, 64);
    __shared__ float r1[4], r2[4];
    if (lane == 0) r1[wid] = s;
    __syncthreads();
    float mean = (r1[0] + r1[1] + r1[2] + r1[3]) * (1.0f / 256.0f);
    float dv = v - mean;
    float s2 = dv * dv;
    #pragma unroll
    for (int o = 32; o; o >>= 1) s2 += __shfl_xor(s2, o, 64);
    if (lane == 0) r2[wid] = s2;
    __syncthreads();
    float var = (r2[0] + r2[1] + r2[2] + r2[3]) * (1.0f / 256.0f);
    float outv = dv * rsqrtf(var + 1e-5f) * g[d] + bt[d];
    if (outf) outf[idx] = outv;
    if (outb) outb[idx] = f2bfu(outv);
}

// ---------------------------------------------------------------------------
extern "C" void kernel_launch(void* const* d_in, const int* in_sizes, int n_in,
                              void* d_out, int out_size, void* d_ws, size_t ws_size,
                              hipStream_t stream)
{
    const float* xin   = (const float*)d_in[0];
    const float* scale = (const float*)d_in[1];
    const float* Win_a = (const float*)d_in[2];
    const float* bin_a = (const float*)d_in[3];
    const float* Wout_a= (const float*)d_in[4];
    const float* bout_a= (const float*)d_in[5];
    const float* Win_e = (const float*)d_in[6];
    const float* bin_e = (const float*)d_in[7];
    const float* Wout_e= (const float*)d_in[8];
    const float* bout_e= (const float*)d_in[9];
    const float* ln1_g = (const float*)d_in[10];
    const float* ln1_b = (const float*)d_in[11];
    const float* ln2_g = (const float*)d_in[12];
    const float* ln2_b = (const float*)d_in[13];
    const float* W1    = (const float*)d_in[14];
    const float* b1    = (const float*)d_in[15];
    const float* W2    = (const float*)d_in[16];
    const float* b2    = (const float*)d_in[17];
    const float* lnf_g = (const float*)d_in[18];
    const float* lnf_b = (const float*)d_in[19];

    char* ws = (char*)d_ws;
    float* X    = (float*)ws;                     ws += (size_t)NTOK * DD * 4;
    float* X2   = (float*)ws;                     ws += (size_t)NTOK * DD * 4;
    float* P    = (float*)ws;                     ws += (size_t)NTOK * DD * 4;
    unsigned short* Xb   = (unsigned short*)ws;   ws += (size_t)NTOK * DD * 2;
    unsigned short* Xlb  = (unsigned short*)ws;   ws += (size_t)NTOK * DD * 2;
    unsigned short* X2b  = (unsigned short*)ws;   ws += (size_t)NTOK * DD * 2;
    unsigned short* ATb  = (unsigned short*)ws;   ws += (size_t)NTOK * DD * 2;
    unsigned short* QKVb = (unsigned short*)ws;   ws += (size_t)NTOK * D3 * 2;
    unsigned short* QKVl = (unsigned short*)ws;   ws += (size_t)NTOK * D3 * 2;
    unsigned short* HMLb = (unsigned short*)ws;   ws += (size_t)NTOK * MLP * 2;
    unsigned short* Wb   = (unsigned short*)ws;   ws += (size_t)W_TOT * 2;
    unsigned short* Wl0  = (unsigned short*)ws;   ws += (size_t)WL0 * 2;

    unsigned short* WinA_b  = Wb + 0;
    unsigned short* WoutA_b = Wb + 393216;
    unsigned short* WinE_b  = Wb + 524288;
    unsigned short* WoutE_b = Wb + 917504;
    unsigned short* W1_b    = Wb + 1048576;
    unsigned short* W2_b    = Wb + 1572864;

    conv_weights<<<W_TOT / 256, 256, 0, stream>>>(
        Win_a, Wout_a, Win_e, Wout_e, W1, W2, Wb, Wl0);
    add_pos_kernel<<<(NTOK * DD + 255) / 256, 256, 0, stream>>>(
        xin, scale, X, Xb, Xlb, NTOK * DD);

    float* cur = X;            float* oth = X2;
    unsigned short* curb = Xb; unsigned short* othb = X2b;

    for (int l = 0; l < 2; l++) {
        // --- full self-attention
        if (l == 0) {
            // precision path: pos-ramp -> O(100s) scores; hi/lo split bf16
            gemm_mfma_split<<<dim3(D3 / 128, NTOK / 128), 256, 0, stream>>>(
                Xb, Xlb, WinA_b, Wl0, bin_a, QKVb, QKVl, NTOK, D3, DD);
            attn_mfma<true><<<dim3(SS / 64, HH, BB), 256, 0, stream>>>(
                QKVb, QKVl, ATb, 1 << 28);
        } else {
            gemm_mfma<<<dim3(D3 / 128, NTOK / 128), 256, 0, stream>>>(
                curb, WinA_b + (size_t)l * D3 * DD, bin_a + (size_t)l * D3,
                nullptr, nullptr, QKVb, NTOK, D3, DD, 0);
            attn_mfma<false><<<dim3(SS / 64, HH, BB), 256, 0, stream>>>(
                QKVb, nullptr, ATb, 1 << 28);
        }
        gemm_mfma<<<dim3(DD / 128, NTOK / 128), 256, 0, stream>>>(
            ATb, WoutA_b + (size_t)l * DD * DD, bout_a + (size_t)l * DD,
            nullptr, P, nullptr, NTOK, DD, DD, 0);
        ln_kernel<<<NTOK, 256, 0, stream>>>(
            P, cur, ln1_g + l * DD, ln1_b + l * DD, oth, othb);

        // --- banded self-attention (|i-j| <= 64) — post-LN input, bf16-safe
        gemm_mfma<<<dim3(D3 / 128, NTOK / 128), 256, 0, stream>>>(
            othb, WinE_b + (size_t)l * D3 * DD, bin_e + (size_t)l * D3,
            nullptr, nullptr, QKVb, NTOK, D3, DD, 0);
        attn_mfma<false><<<dim3(SS / 64, HH, BB), 256, 0, stream>>>(
            QKVb, nullptr, ATb, 64);
        gemm_mfma<<<dim3(DD / 128, NTOK / 128), 256, 0, stream>>>(
            ATb, WoutE_b + (size_t)l * DD * DD, bout_e + (size_t)l * DD,
            nullptr, P, nullptr, NTOK, DD, DD, 0);
        ln_kernel<<<NTOK, 256, 0, stream>>>(
            P, oth, ln2_g + l * DD, ln2_b + l * DD, cur, curb);
        // attended now in cur/curb

        // --- MLP with exact gelu, fused residual
        gemm_mfma<<<dim3(MLP / 128, NTOK / 128), 256, 0, stream>>>(
            curb, W1_b + (size_t)l * MLP * DD, b1 + (size_t)l * MLP,
            nullptr, nullptr, HMLb, NTOK, MLP, DD, 1);
        gemm_mfma<<<dim3(DD / 128, NTOK / 128), 256, 0, stream>>>(
            HMLb, W2_b + (size_t)l * DD * MLP, b2 + (size_t)l * DD,
            cur, oth, othb, NTOK, DD, MLP, 0);

        float* tf = cur; cur = oth; oth = tf;
        unsigned short* tb = curb; curb = othb; othb = tb;
    }

    ln_kernel<<<NTOK, 256, 0, stream>>>(cur, nullptr, lnf_g, lnf_b,
                                        (float*)d_out, nullptr);
}

// Round 7
// 364.840 us; speedup vs baseline: 8.6497x; 1.2174x over previous
//
#include <hip/hip_runtime.h>
#include <math.h>

// Problem constants
#define BB 4
#define SS 1024
#define DD 256
#define HH 8
#define HD 32
#define D3 768
#define MLP 1024
#define NTOK (BB * SS)   // 4096
#define NSEG 2           // split-K segments for full attention

typedef __attribute__((ext_vector_type(8))) short short8;
typedef __attribute__((ext_vector_type(4))) float f32x4;

__device__ __forceinline__ unsigned short f2bfu(float f) {
    union { float f; unsigned i; } u; u.f = f;
    unsigned r = u.i + 0x7fffu + ((u.i >> 16) & 1u);   // RNE
    return (unsigned short)(r >> 16);
}
__device__ __forceinline__ float bfu2f(unsigned short h) {
    union { unsigned i; float f; } u; u.i = ((unsigned)h) << 16; return u.f;
}

// ---------------------------------------------------------------------------
// weights fp32 -> bf16; also lo-part for Win_a layer 0 (hi/lo split path)
#define W_TOT 2097152
#define WL0   196608   // 768*256 = Win_a layer 0
__global__ __launch_bounds__(256) void conv_weights(
    const float* __restrict__ a0, const float* __restrict__ a1,
    const float* __restrict__ a2, const float* __restrict__ a3,
    const float* __restrict__ a4, const float* __restrict__ a5,
    unsigned short* __restrict__ out, unsigned short* __restrict__ out_lo)
{
    int i = blockIdx.x * 256 + threadIdx.x;
    const float* s; int off;
    if      (i <  393216) { s = a0; off = 0;       }
    else if (i <  524288) { s = a1; off = 393216;  }
    else if (i <  917504) { s = a2; off = 524288;  }
    else if (i < 1048576) { s = a3; off = 917504;  }
    else if (i < 1572864) { s = a4; off = 1048576; }
    else                  { s = a5; off = 1572864; }
    float v = s[i - off];
    unsigned short h = f2bfu(v);
    out[i] = h;
    if (i < WL0) out_lo[i] = f2bfu(v - bfu2f(h));
}

// ---------------------------------------------------------------------------
// x (f32) + positional encoding -> fp32 + bf16 hi + bf16 lo
__global__ __launch_bounds__(256) void add_pos_kernel(
    const float* __restrict__ x, const float* __restrict__ scale,
    float* __restrict__ out, unsigned short* __restrict__ outh,
    unsigned short* __restrict__ outl, int n)
{
    int i = blockIdx.x * 256 + threadIdx.x;
    if (i >= n) return;
    int s = (i >> 8) & (SS - 1);
    float v = x[i] + (float)s * scale[0];
    out[i] = v;
    unsigned short h = f2bfu(v);
    outh[i] = h;
    outl[i] = f2bfu(v - bfu2f(h));
}

// ---------------------------------------------------------------------------
// MFMA GEMM: C[M,N] = A[M,K](bf16) @ W[N,K]^T(bf16) + bias(f32)
//            [+gelu] [+resid f32] -> outf (f32) and/or outb (bf16)
// 64x128 block tile, 256 thr = 4 waves (2x2 of 32x64), BK=32.
// 64-row M-tile doubles block count vs 128 (grids were < 1 block/CU).
#define LDP 40
__global__ __launch_bounds__(256) void gemm_mfma(
    const unsigned short* __restrict__ A, const unsigned short* __restrict__ W,
    const float* __restrict__ bias, const float* __restrict__ resid,
    float* __restrict__ outf, unsigned short* __restrict__ outb,
    int M, int N, int K, int act)
{
    __shared__ __align__(16) unsigned short As[64 * LDP];
    __shared__ __align__(16) unsigned short Bs[128 * LDP];
    const int t = threadIdx.x;
    const int lane = t & 63, wave = t >> 6;
    const int wr = wave >> 1, wc = wave & 1;
    const int m0 = blockIdx.y * 64, n0 = blockIdx.x * 128;
    const int sr = t >> 2;
    const int sc = (t & 3) * 8;

    const unsigned short* Ag = A + (size_t)(m0 + sr) * K + sc;
    const unsigned short* Wg = W + (size_t)(n0 + sr) * K + sc;

    f32x4 acc[2][4];
    #pragma unroll
    for (int i = 0; i < 2; i++)
        #pragma unroll
        for (int j = 0; j < 4; j++)
            acc[i][j] = (f32x4){0.f, 0.f, 0.f, 0.f};

    const int lm = lane & 15, lk = (lane >> 4) * 8;

    for (int k0 = 0; k0 < K; k0 += 32) {
        uint4 a0 = *(const uint4*)(Ag + k0);
        uint4 b0 = *(const uint4*)(Wg + k0);
        uint4 b1 = *(const uint4*)(Wg + (size_t)64 * K + k0);
        __syncthreads();
        *(uint4*)&As[sr * LDP + sc]        = a0;
        *(uint4*)&Bs[sr * LDP + sc]        = b0;
        *(uint4*)&Bs[(sr + 64) * LDP + sc] = b1;
        __syncthreads();

        short8 af[2], bf[4];
        #pragma unroll
        for (int i = 0; i < 2; i++)
            af[i] = *(const short8*)&As[(wr * 32 + i * 16 + lm) * LDP + lk];
        #pragma unroll
        for (int j = 0; j < 4; j++)
            bf[j] = *(const short8*)&Bs[(wc * 64 + j * 16 + lm) * LDP + lk];
        #pragma unroll
        for (int i = 0; i < 2; i++)
            #pragma unroll
            for (int j = 0; j < 4; j++)
                acc[i][j] = __builtin_amdgcn_mfma_f32_16x16x32_bf16(
                    af[i], bf[j], acc[i][j], 0, 0, 0);
    }

    const int lq = lane >> 4;
    #pragma unroll
    for (int j = 0; j < 4; j++) {
        int col = n0 + wc * 64 + j * 16 + lm;
        float bv = bias[col];
        #pragma unroll
        for (int i = 0; i < 2; i++) {
            #pragma unroll
            for (int r = 0; r < 4; r++) {
                int row = m0 + wr * 32 + i * 16 + lq * 4 + r;
                float v = acc[i][j][r] + bv;
                if (act) v = 0.5f * v * (1.0f + erff(v * 0.70710678118654752f));
                size_t idx = (size_t)row * N + col;
                if (resid) v += resid[idx];
                if (outf) outf[idx] = v;
                if (outb) outb[idx] = f2bfu(v);
            }
        }
    }
}

// ---------------------------------------------------------------------------
// Split (hi/lo bf16 ~ fp32) MFMA GEMM for the layer-0 QKV projection:
// C = (Ah+Al)(Wh+Wl)^T + bias ~= Ah Wh + Ah Wl + Al Wh. Outputs hi/lo bf16.
// Same 64x128 tiling.
__global__ __launch_bounds__(256) void gemm_mfma_split(
    const unsigned short* __restrict__ Ah, const unsigned short* __restrict__ Al,
    const unsigned short* __restrict__ Wh, const unsigned short* __restrict__ Wl,
    const float* __restrict__ bias,
    unsigned short* __restrict__ outh, unsigned short* __restrict__ outl,
    int M, int N, int K)
{
    __shared__ __align__(16) unsigned short Ash[64 * LDP];
    __shared__ __align__(16) unsigned short Asl[64 * LDP];
    __shared__ __align__(16) unsigned short Bsh[128 * LDP];
    __shared__ __align__(16) unsigned short Bsl[128 * LDP];
    const int t = threadIdx.x;
    const int lane = t & 63, wave = t >> 6;
    const int wr = wave >> 1, wc = wave & 1;
    const int m0 = blockIdx.y * 64, n0 = blockIdx.x * 128;
    const int sr = t >> 2;
    const int sc = (t & 3) * 8;

    const size_t oA = (size_t)(m0 + sr) * K + sc;
    const size_t oW = (size_t)(n0 + sr) * K + sc;

    f32x4 acc[2][4];
    #pragma unroll
    for (int i = 0; i < 2; i++)
        #pragma unroll
        for (int j = 0; j < 4; j++)
            acc[i][j] = (f32x4){0.f, 0.f, 0.f, 0.f};

    const int lm = lane & 15, lk = (lane >> 4) * 8;

    for (int k0 = 0; k0 < K; k0 += 32) {
        uint4 ah0 = *(const uint4*)(Ah + oA + k0);
        uint4 al0 = *(const uint4*)(Al + oA + k0);
        uint4 bh0 = *(const uint4*)(Wh + oW + k0);
        uint4 bh1 = *(const uint4*)(Wh + oW + (size_t)64 * K + k0);
        uint4 bl0 = *(const uint4*)(Wl + oW + k0);
        uint4 bl1 = *(const uint4*)(Wl + oW + (size_t)64 * K + k0);
        __syncthreads();
        *(uint4*)&Ash[sr * LDP + sc]        = ah0;
        *(uint4*)&Asl[sr * LDP + sc]        = al0;
        *(uint4*)&Bsh[sr * LDP + sc]        = bh0;
        *(uint4*)&Bsh[(sr + 64) * LDP + sc] = bh1;
        *(uint4*)&Bsl[sr * LDP + sc]        = bl0;
        *(uint4*)&Bsl[(sr + 64) * LDP + sc] = bl1;
        __syncthreads();

        short8 afh[2], afl[2], bfh[4], bfl[4];
        #pragma unroll
        for (int i = 0; i < 2; i++) {
            afh[i] = *(const short8*)&Ash[(wr * 32 + i * 16 + lm) * LDP + lk];
            afl[i] = *(const short8*)&Asl[(wr * 32 + i * 16 + lm) * LDP + lk];
        }
        #pragma unroll
        for (int j = 0; j < 4; j++) {
            bfh[j] = *(const short8*)&Bsh[(wc * 64 + j * 16 + lm) * LDP + lk];
            bfl[j] = *(const short8*)&Bsl[(wc * 64 + j * 16 + lm) * LDP + lk];
        }
        #pragma unroll
        for (int i = 0; i < 2; i++)
            #pragma unroll
            for (int j = 0; j < 4; j++) {
                acc[i][j] = __builtin_amdgcn_mfma_f32_16x16x32_bf16(
                    afl[i], bfh[j], acc[i][j], 0, 0, 0);
                acc[i][j] = __builtin_amdgcn_mfma_f32_16x16x32_bf16(
                    afh[i], bfl[j], acc[i][j], 0, 0, 0);
                acc[i][j] = __builtin_amdgcn_mfma_f32_16x16x32_bf16(
                    afh[i], bfh[j], acc[i][j], 0, 0, 0);
            }
    }

    const int lq = lane >> 4;
    #pragma unroll
    for (int j = 0; j < 4; j++) {
        int col = n0 + wc * 64 + j * 16 + lm;
        float bv = bias[col];
        #pragma unroll
        for (int i = 0; i < 2; i++) {
            #pragma unroll
            for (int r = 0; r < 4; r++) {
                int row = m0 + wr * 32 + i * 16 + lq * 4 + r;
                float v = acc[i][j][r] + bv;
                size_t idx = (size_t)row * N + col;
                unsigned short h = f2bfu(v);
                outh[idx] = h;
                outl[idx] = f2bfu(v - bfu2f(h));
            }
        }
    }
}

// ---------------------------------------------------------------------------
// MFMA flash attention with optional split-K. Block = 4 waves per
// (b, h, 64-q-tile, seg). Wave w owns q rows [i0+16w, i0+16w+16).
// nseg==1: normalized bf16 out.  nseg>1: unnormalized partial O (f32) + (m,l).
template<bool SPLIT>
__global__ __launch_bounds__(256) void attn_mfma(
    const unsigned short* __restrict__ qkvh,
    const unsigned short* __restrict__ qkvl,
    unsigned short* __restrict__ outb,
    float* __restrict__ Of, float2* __restrict__ Ml,
    int win, int nseg)
{
    __shared__ __align__(16) unsigned short Ks [64 * 40];
    __shared__ __align__(16) unsigned short Vt [32 * 72];
    __shared__ __align__(16) unsigned short Ps [64 * 72];
    __shared__ __align__(16) unsigned short Ksl[SPLIT ? 64 * 40 : 8];
    __shared__ __align__(16) unsigned short Vtl[SPLIT ? 32 * 72 : 8];

    const int t = threadIdx.x;
    const int wave = t >> 6, lane = t & 63;
    const int lm = lane & 15, quad = lane >> 4;
    const int i0 = blockIdx.x * 64, h = blockIdx.y;
    const int z = blockIdx.z;
    const int b = z / nseg, seg = z - b * nseg;
    const int sr = t >> 2, sc8 = (t & 3) * 8;

    // Q A-fragments straight from global: A[m=lm][k=quad*8+j]
    const size_t qoff = ((size_t)(b * SS) + i0 + 16 * wave + lm) * D3 + h * HD + quad * 8;
    short8 qh = *(const short8*)(qkvh + qoff);
    short8 ql = {};
    if constexpr (SPLIT) ql = *(const short8*)(qkvl + qoff);

    float m[4], l[4];
    f32x4 o[2];
    #pragma unroll
    for (int r = 0; r < 4; r++) { m[r] = -1e30f; l[r] = 0.f; }
    o[0] = (f32x4){0.f, 0.f, 0.f, 0.f};
    o[1] = (f32x4){0.f, 0.f, 0.f, 0.f};

    int t0 = 0, t1 = SS / 64 - 1;
    const bool masked = (win < SS);
    if (masked) {
        t0 = (i0 - win) >> 6;        if (t0 < 0) t0 = 0;
        t1 = (i0 + 63 + win) >> 6;   if (t1 > SS / 64 - 1) t1 = SS / 64 - 1;
    }
    // this segment's tile range
    const int per = (t1 - t0 + nseg) / nseg;
    const int s0 = t0 + seg * per;
    const int s1 = (s0 + per - 1 < t1) ? (s0 + per - 1) : t1;
    const float scl = 0.17677669529663688f;  // 1/sqrt(32)

    for (int kt = s0; kt <= s1; kt++) {
        const int k0 = kt * 64;
        __syncthreads();   // all waves done reading Ks/Vt of previous tile
        {
            const size_t koff = ((size_t)(b * SS) + k0 + sr) * D3 + DD + h * HD + sc8;
            short8 kv = *(const short8*)(qkvh + koff);
            *(short8*)&Ks[sr * 40 + sc8] = kv;
            short8 vv = *(const short8*)(qkvh + koff + DD);
            #pragma unroll
            for (int c = 0; c < 8; c++)
                Vt[(sc8 + c) * 72 + sr] = ((unsigned short*)&vv)[c];
            if constexpr (SPLIT) {
                short8 kl = *(const short8*)(qkvl + koff);
                *(short8*)&Ksl[sr * 40 + sc8] = kl;
                short8 vl = *(const short8*)(qkvl + koff + DD);
                #pragma unroll
                for (int c = 0; c < 8; c++)
                    Vtl[(sc8 + c) * 72 + sr] = ((unsigned short*)&vl)[c];
            }
        }
        __syncthreads();

        // ---- scores: 4 MFMAs (x3 terms when SPLIT); C: col=16cb+lm, row=quad*4+r
        f32x4 s[4];
        #pragma unroll
        for (int cb = 0; cb < 4; cb++) {
            short8 kf = *(const short8*)&Ks[(16 * cb + lm) * 40 + quad * 8];
            f32x4 a = (f32x4){0.f, 0.f, 0.f, 0.f};
            if constexpr (SPLIT) {
                short8 kfl = *(const short8*)&Ksl[(16 * cb + lm) * 40 + quad * 8];
                a = __builtin_amdgcn_mfma_f32_16x16x32_bf16(ql, kf,  a, 0, 0, 0);
                a = __builtin_amdgcn_mfma_f32_16x16x32_bf16(qh, kfl, a, 0, 0, 0);
            }
            a = __builtin_amdgcn_mfma_f32_16x16x32_bf16(qh, kf, a, 0, 0, 0);
            s[cb] = a;
        }

        float sc[4][4];
        #pragma unroll
        for (int cb = 0; cb < 4; cb++)
            #pragma unroll
            for (int r = 0; r < 4; r++) {
                float v = s[cb][r] * scl;
                if (masked) {
                    int di = (i0 + 16 * wave + quad * 4 + r) - (k0 + 16 * cb + lm);
                    if (di > win || di < -win) v = -1e30f;
                }
                sc[cb][r] = v;
            }

        // ---- online softmax per row (16-lane quad-group reductions)
        #pragma unroll
        for (int r = 0; r < 4; r++) {
            float tm = fmaxf(fmaxf(sc[0][r], sc[1][r]), fmaxf(sc[2][r], sc[3][r]));
            tm = fmaxf(tm, __shfl_xor(tm, 1, 64));
            tm = fmaxf(tm, __shfl_xor(tm, 2, 64));
            tm = fmaxf(tm, __shfl_xor(tm, 4, 64));
            tm = fmaxf(tm, __shfl_xor(tm, 8, 64));
            float mn = fmaxf(m[r], tm);
            float alpha = __expf(m[r] - mn);
            float p0 = __expf(sc[0][r] - mn), p1 = __expf(sc[1][r] - mn);
            float p2 = __expf(sc[2][r] - mn), p3 = __expf(sc[3][r] - mn);
            float ps = p0 + p1 + p2 + p3;
            ps += __shfl_xor(ps, 1, 64);
            ps += __shfl_xor(ps, 2, 64);
            ps += __shfl_xor(ps, 4, 64);
            ps += __shfl_xor(ps, 8, 64);
            l[r] = l[r] * alpha + ps;
            o[0][r] *= alpha;
            o[1][r] *= alpha;
            m[r] = mn;
            const int pr = (16 * wave + quad * 4 + r) * 72 + lm;
            Ps[pr +  0] = f2bfu(p0);
            Ps[pr + 16] = f2bfu(p1);
            Ps[pr + 32] = f2bfu(p2);
            Ps[pr + 48] = f2bfu(p3);
        }
        // Ps region is wave-private (wave reads only its own 16 rows) — no barrier

        // ---- PV: o[16x32] += P[16x64] @ V[64x32]
        #pragma unroll
        for (int kc = 0; kc < 2; kc++) {
            short8 pf = *(const short8*)&Ps[(16 * wave + lm) * 72 + 32 * kc + quad * 8];
            #pragma unroll
            for (int nh = 0; nh < 2; nh++) {
                short8 vf = *(const short8*)&Vt[(16 * nh + lm) * 72 + 32 * kc + quad * 8];
                o[nh] = __builtin_amdgcn_mfma_f32_16x16x32_bf16(pf, vf, o[nh], 0, 0, 0);
                if constexpr (SPLIT) {
                    short8 vfl = *(const short8*)&Vtl[(16 * nh + lm) * 72 + 32 * kc + quad * 8];
                    o[nh] = __builtin_amdgcn_mfma_f32_16x16x32_bf16(pf, vfl, o[nh], 0, 0, 0);
                }
            }
        }
    }

    if (nseg == 1) {
        // ---- direct write: row = i0+16w+quad*4+r, col = h*HD + 16nh + lm
        #pragma unroll
        for (int r = 0; r < 4; r++) {
            float invl = 1.0f / l[r];
            size_t base = ((size_t)(b * SS) + i0 + 16 * wave + quad * 4 + r) * DD + h * HD + lm;
            outb[base]      = f2bfu(o[0][r] * invl);
            outb[base + 16] = f2bfu(o[1][r] * invl);
        }
    } else {
        // ---- partial write: unnormalized o (f32) + per-row (m,l)
        #pragma unroll
        for (int r = 0; r < 4; r++) {
            int row = i0 + 16 * wave + quad * 4 + r;
            size_t base = ((size_t)(seg * NTOK) + b * SS + row) * DD + h * HD + lm;
            Of[base]      = o[0][r];
            Of[base + 16] = o[1][r];
            if (lm == 0)
                Ml[((size_t)(seg * NTOK) + b * SS + row) * HH + h] =
                    make_float2(m[r], l[r]);
        }
    }
}

// ---------------------------------------------------------------------------
// Combine NSEG=2 attention partials: o = sum_s o_s e^{m_s-M} / sum_s l_s e^{m_s-M}
__global__ __launch_bounds__(256) void attn_combine(
    const float* __restrict__ Of, const float2* __restrict__ Ml,
    unsigned short* __restrict__ out)
{
    int i = blockIdx.x * 256 + threadIdx.x;   // NTOK*DD threads
    int token = i >> 8;
    int h = (i & 255) >> 5;
    float2 a = Ml[(size_t)token * HH + h];
    float2 c = Ml[((size_t)NTOK + token) * HH + h];
    float M = fmaxf(a.x, c.x);
    float w0 = __expf(a.x - M), w1 = __expf(c.x - M);
    float ov = Of[i] * w0 + Of[(size_t)NTOK * DD + i] * w1;
    float lv = a.y * w0 + c.y * w1;
    out[i] = f2bfu(ov / lv);
}

// ---------------------------------------------------------------------------
// out = LN(a [+ r]) * g + b — one WAVE per row (no barriers), 4 rows/block.
__global__ __launch_bounds__(256) void ln_kernel(
    const float* __restrict__ a, const float* __restrict__ r,
    const float* __restrict__ g, const float* __restrict__ bt,
    float* __restrict__ outf, unsigned short* __restrict__ outb)
{
    const int wave = threadIdx.x >> 6, lane = threadIdx.x & 63;
    const int row = blockIdx.x * 4 + wave;
    const size_t base = (size_t)row * DD + lane * 4;
    float4 v = *(const float4*)(a + base);
    if (r) {
        float4 rv = *(const float4*)(r + base);
        v.x += rv.x; v.y += rv.y; v.z += rv.z; v.w += rv.w;
    }
    float s = v.x + v.y + v.z + v.w;
    #pragma unroll
    for (int off = 1; off < 64; off <<= 1) s += __shfl_xor(s, off, 64);
    float mean = s * (1.0f / 256.0f);
    float4 dv = { v.x - mean, v.y - mean, v.z - mean, v.w - mean };
    float s2 = dv.x * dv.x + dv.y * dv.y + dv.z * dv.z + dv.w * dv.w;
    #pragma unroll
    for (int off = 1; off < 64; off <<= 1) s2 += __shfl_xor(s2, off, 64);
    float rst = rsqrtf(s2 * (1.0f / 256.0f) + 1e-5f);
    float4 g4 = *(const float4*)(g + lane * 4);
    float4 b4 = *(const float4*)(bt + lane * 4);
    float4 ov = { dv.x * rst * g4.x + b4.x, dv.y * rst * g4.y + b4.y,
                  dv.z * rst * g4.z + b4.z, dv.w * rst * g4.w + b4.w };
    if (outf) *(float4*)(outf + base) = ov;
    if (outb) {
        ushort4 u = { f2bfu(ov.x), f2bfu(ov.y), f2bfu(ov.z), f2bfu(ov.w) };
        *(ushort4*)(outb + base) = u;
    }
}

// ---------------------------------------------------------------------------
extern "C" void kernel_launch(void* const* d_in, const int* in_sizes, int n_in,
                              void* d_out, int out_size, void* d_ws, size_t ws_size,
                              hipStream_t stream)
{
    const float* xin   = (const float*)d_in[0];
    const float* scale = (const float*)d_in[1];
    const float* Win_a = (const float*)d_in[2];
    const float* bin_a = (const float*)d_in[3];
    const float* Wout_a= (const float*)d_in[4];
    const float* bout_a= (const float*)d_in[5];
    const float* Win_e = (const float*)d_in[6];
    const float* bin_e = (const float*)d_in[7];
    const float* Wout_e= (const float*)d_in[8];
    const float* bout_e= (const float*)d_in[9];
    const float* ln1_g = (const float*)d_in[10];
    const float* ln1_b = (const float*)d_in[11];
    const float* ln2_g = (const float*)d_in[12];
    const float* ln2_b = (const float*)d_in[13];
    const float* W1    = (const float*)d_in[14];
    const float* b1    = (const float*)d_in[15];
    const float* W2    = (const float*)d_in[16];
    const float* b2    = (const float*)d_in[17];
    const float* lnf_g = (const float*)d_in[18];
    const float* lnf_b = (const float*)d_in[19];

    char* ws = (char*)d_ws;
    float* X    = (float*)ws;                     ws += (size_t)NTOK * DD * 4;
    float* X2   = (float*)ws;                     ws += (size_t)NTOK * DD * 4;
    float* P    = (float*)ws;                     ws += (size_t)NTOK * DD * 4;
    unsigned short* Xb   = (unsigned short*)ws;   ws += (size_t)NTOK * DD * 2;
    unsigned short* Xlb  = (unsigned short*)ws;   ws += (size_t)NTOK * DD * 2;
    unsigned short* X2b  = (unsigned short*)ws;   ws += (size_t)NTOK * DD * 2;
    unsigned short* ATb  = (unsigned short*)ws;   ws += (size_t)NTOK * DD * 2;
    unsigned short* QKVb = (unsigned short*)ws;   ws += (size_t)NTOK * D3 * 2;
    unsigned short* QKVl = (unsigned short*)ws;   ws += (size_t)NTOK * D3 * 2;
    unsigned short* HMLb = (unsigned short*)ws;   ws += (size_t)NTOK * MLP * 2;
    unsigned short* Wb   = (unsigned short*)ws;   ws += (size_t)W_TOT * 2;
    unsigned short* Wl0  = (unsigned short*)ws;   ws += (size_t)WL0 * 2;
    float2* Ml           = (float2*)ws;           ws += (size_t)NSEG * NTOK * HH * 8;

    // Partial-O for split-K attention ALIASES HMLb (8.39 MB each, lifetimes
    // disjoint: Of lives only between QKV-proj and combine; HMLb only in MLP).
    float* Of = (float*)HMLb;

    unsigned short* WinA_b  = Wb + 0;
    unsigned short* WoutA_b = Wb + 393216;
    unsigned short* WinE_b  = Wb + 524288;
    unsigned short* WoutE_b = Wb + 917504;
    unsigned short* W1_b    = Wb + 1048576;
    unsigned short* W2_b    = Wb + 1572864;

    conv_weights<<<W_TOT / 256, 256, 0, stream>>>(
        Win_a, Wout_a, Win_e, Wout_e, W1, W2, Wb, Wl0);
    add_pos_kernel<<<(NTOK * DD + 255) / 256, 256, 0, stream>>>(
        xin, scale, X, Xb, Xlb, NTOK * DD);

    float* cur = X;            float* oth = X2;
    unsigned short* curb = Xb; unsigned short* othb = X2b;

    for (int l = 0; l < 2; l++) {
        // --- full self-attention (split-K, NSEG segments)
        if (l == 0) {
            // precision path: pos-ramp -> O(100s) scores; hi/lo split bf16
            gemm_mfma_split<<<dim3(D3 / 128, NTOK / 64), 256, 0, stream>>>(
                Xb, Xlb, WinA_b, Wl0, bin_a, QKVb, QKVl, NTOK, D3, DD);
            attn_mfma<true><<<dim3(SS / 64, HH, BB * NSEG), 256, 0, stream>>>(
                QKVb, QKVl, nullptr, Of, Ml, 1 << 28, NSEG);
        } else {
            gemm_mfma<<<dim3(D3 / 128, NTOK / 64), 256, 0, stream>>>(
                curb, WinA_b + (size_t)l * D3 * DD, bin_a + (size_t)l * D3,
                nullptr, nullptr, QKVb, NTOK, D3, DD, 0);
            attn_mfma<false><<<dim3(SS / 64, HH, BB * NSEG), 256, 0, stream>>>(
                QKVb, nullptr, nullptr, Of, Ml, 1 << 28, NSEG);
        }
        attn_combine<<<NTOK * DD / 256, 256, 0, stream>>>(Of, Ml, ATb);
        gemm_mfma<<<dim3(DD / 128, NTOK / 64), 256, 0, stream>>>(
            ATb, WoutA_b + (size_t)l * DD * DD, bout_a + (size_t)l * DD,
            nullptr, P, nullptr, NTOK, DD, DD, 0);
        ln_kernel<<<NTOK / 4, 256, 0, stream>>>(
            P, cur, ln1_g + l * DD, ln1_b + l * DD, oth, othb);

        // --- banded self-attention (|i-j| <= 64) — post-LN input, bf16-safe
        gemm_mfma<<<dim3(D3 / 128, NTOK / 64), 256, 0, stream>>>(
            othb, WinE_b + (size_t)l * D3 * DD, bin_e + (size_t)l * D3,
            nullptr, nullptr, QKVb, NTOK, D3, DD, 0);
        attn_mfma<false><<<dim3(SS / 64, HH, BB), 256, 0, stream>>>(
            QKVb, nullptr, ATb, nullptr, nullptr, 64, 1);
        gemm_mfma<<<dim3(DD / 128, NTOK / 64), 256, 0, stream>>>(
            ATb, WoutE_b + (size_t)l * DD * DD, bout_e + (size_t)l * DD,
            nullptr, P, nullptr, NTOK, DD, DD, 0);
        ln_kernel<<<NTOK / 4, 256, 0, stream>>>(
            P, oth, ln2_g + l * DD, ln2_b + l * DD, cur, curb);
        // attended now in cur/curb

        // --- MLP with exact gelu, fused residual
        gemm_mfma<<<dim3(MLP / 128, NTOK / 64), 256, 0, stream>>>(
            curb, W1_b + (size_t)l * MLP * DD, b1 + (size_t)l * MLP,
            nullptr, nullptr, HMLb, NTOK, MLP, DD, 1);
        gemm_mfma<<<dim3(DD / 128, NTOK / 64), 256, 0, stream>>>(
            HMLb, W2_b + (size_t)l * DD * MLP, b2 + (size_t)l * DD,
            cur, oth, othb, NTOK, DD, MLP, 0);

        float* tf = cur; cur = oth; oth = tf;
        unsigned short* tb = curb; curb = othb; othb = tb;
    }

    ln_kernel<<<NTOK / 4, 256, 0, stream>>>(cur, nullptr, lnf_g, lnf_b,
                                            (float*)d_out, nullptr);
}